// Round 1
// baseline (2318.095 us; speedup 1.0000x reference)
//
#include <hip/hip_runtime.h>
#include <hip/hip_bf16.h>

#define BB 4096
#define KK 4
#define TT 5
#define NNODE 5
#define GTOT (BB * TT * NNODE)   // 102400 graphs; emb row = b*25 + t*5 + node

template<typename ET> __device__ __forceinline__ float et2f(ET v);
template<> __device__ __forceinline__ float et2f<float>(float v) { return v; }
template<> __device__ __forceinline__ float et2f<__hip_bfloat16>(__hip_bfloat16 v) { return __bfloat162float(v); }
template<typename ET> __device__ __forceinline__ ET f2et(float v);
template<> __device__ __forceinline__ float f2et<float>(float v) { return v; }
template<> __device__ __forceinline__ __hip_bfloat16 f2et<__hip_bfloat16>(float v) { return __float2bfloat16(v); }

// ---------------------------------------------------------------------------
// Kernel 1: GAT-temporal encoder. One wave (64 lanes) per graph, 4 graphs/block.
// ---------------------------------------------------------------------------
template<typename ET>
__global__ __launch_bounds__(256) void gat_kernel(
    const float* __restrict__ self_feat, const float* __restrict__ nbr_feat,
    const float* __restrict__ W_in, const float* __restrict__ b_in,
    const float* __restrict__ ln_g, const float* __restrict__ ln_b,
    const float* __restrict__ W_coop, const float* __restrict__ as_c, const float* __restrict__ ad_c,
    const float* __restrict__ W_conf, const float* __restrict__ as_f, const float* __restrict__ ad_f,
    const float* __restrict__ adj_coop, const float* __restrict__ adj_conf,
    ET* __restrict__ emb)
{
    __shared__ __align__(16) float u_sh[2][2][4][68];   // [src/dst][gat][head][f] pad 68
    __shared__ __align__(16) float h_sh[4][12][68];     // [wave][n][f] pad 68 (16B aligned rows)
    __shared__ float sd_sh[4][2][2][4][12];             // [wave][src/dst][gat][head][n]
    __shared__ int   adjm_sh[2][12];                    // bitmask rows

    const int tid  = threadIdx.x;
    const int wave = tid >> 6;
    const int lane = tid & 63;

    // ---- block-wide precompute: u_src/u_dst (graph independent) ----
    for (int v = tid; v < 1024; v += 256) {
        int f = v & 63, h = (v >> 6) & 3, gat = (v >> 8) & 1, sd = (v >> 9) & 1;
        const float* W = gat ? W_conf : W_coop;
        const float* a = sd ? (gat ? ad_f : ad_c) : (gat ? as_f : as_c);
        const float* wp = W + (h * 64 + f) * 32;
        const float* ap = a + h * 32;
        float s = 0.f;
        #pragma unroll
        for (int o = 0; o < 32; ++o) s = fmaf(wp[o], ap[o], s);
        u_sh[sd][gat][h][f] = s;
    }
    if (tid < 24) {
        int gat = tid / 12, n = tid % 12;
        const float* adj = gat ? adj_conf : adj_coop;
        int m = 0;
        for (int c = 0; c < 12; ++c) if (adj[n * 12 + c] > 0.f) m |= (1 << c);
        adjm_sh[gat][n] = m;
    }

    // ---- decode graph id: g = b*25 + t*5 + node ----
    const int g = blockIdx.x * 4 + wave;
    const int b = g / 25;
    const int r = g % 25;
    const int t = r / 5;
    const int node = r % 5;
    const float* x = (node == 0) ? (self_feat + (size_t)(b * 5 + t) * 48)
                                 : (nbr_feat + (size_t)((b * 4 + (node - 1)) * 5 + t) * 48);

    // ---- h = x @ W_in + b_in ; LayerNorm ; ReLU (lane = feature f) ----
    const float w0 = W_in[lane], w1 = W_in[64 + lane], w2 = W_in[128 + lane], w3 = W_in[192 + lane];
    const float bb_ = b_in[lane], lg = ln_g[lane], lb = ln_b[lane];
    float hreg[12];
    #pragma unroll
    for (int n = 0; n < 12; ++n) {
        float x0 = x[n * 4], x1 = x[n * 4 + 1], x2 = x[n * 4 + 2], x3 = x[n * 4 + 3];
        hreg[n] = fmaf(x0, w0, fmaf(x1, w1, fmaf(x2, w2, fmaf(x3, w3, bb_))));
    }
    #pragma unroll
    for (int n = 0; n < 12; ++n) {
        float s = hreg[n], s2 = hreg[n] * hreg[n];
        #pragma unroll
        for (int m = 1; m < 64; m <<= 1) {
            s  += __shfl_xor(s, m, 64);
            s2 += __shfl_xor(s2, m, 64);
        }
        float mu  = s * (1.f / 64.f);
        float var = s2 * (1.f / 64.f) - mu * mu;
        float vv  = (hreg[n] - mu) * rsqrtf(var + 1e-5f) * lg + lb;
        hreg[n] = fmaxf(vv, 0.f);
        h_sh[wave][n][lane] = hreg[n];
    }
    __syncthreads();

    // ---- Wh: each lane owns 4 columns c: gat=c>>1, head=(c&1)*2+hl, o=lane&31 ----
    const int hl = lane >> 5, o = lane & 31;
    float acc[4][12];
    #pragma unroll
    for (int c = 0; c < 4; ++c)
        #pragma unroll
        for (int n = 0; n < 12; ++n) acc[c][n] = 0.f;

    const float* Wp[4];
    Wp[0] = W_coop + (hl)       * 2048 + o;
    Wp[1] = W_coop + (2 + hl)   * 2048 + o;
    Wp[2] = W_conf + (hl)       * 2048 + o;
    Wp[3] = W_conf + (2 + hl)   * 2048 + o;

    for (int f4 = 0; f4 < 16; ++f4) {
        float w[4][4];
        #pragma unroll
        for (int c = 0; c < 4; ++c)
            #pragma unroll
            for (int s = 0; s < 4; ++s) w[c][s] = Wp[c][(f4 * 4 + s) * 32];
        #pragma unroll
        for (int n = 0; n < 12; ++n) {
            float4 hv = *reinterpret_cast<const float4*>(&h_sh[wave][n][f4 * 4]);
            #pragma unroll
            for (int c = 0; c < 4; ++c) {
                acc[c][n] = fmaf(w[c][0], hv.x, acc[c][n]);
                acc[c][n] = fmaf(w[c][1], hv.y, acc[c][n]);
                acc[c][n] = fmaf(w[c][2], hv.z, acc[c][n]);
                acc[c][n] = fmaf(w[c][3], hv.w, acc[c][n]);
            }
        }
    }

    // ---- src/dst scores: 192 dot-64s per graph, 3 per lane ----
    #pragma unroll
    for (int jj = 0; jj < 3; ++jj) {
        int v = lane + 64 * jj;
        int n = v % 12; int q = v / 12;
        int hh2 = q & 3, gg2 = (q >> 2) & 1, sd2 = (q >> 3) & 1;
        const float4* up = reinterpret_cast<const float4*>(&u_sh[sd2][gg2][hh2][0]);
        const float4* hp = reinterpret_cast<const float4*>(&h_sh[wave][n][0]);
        float s = 0.f;
        #pragma unroll
        for (int fq = 0; fq < 16; ++fq) {
            float4 a = up[fq]; float4 bq = hp[fq];
            s = fmaf(a.x, bq.x, s); s = fmaf(a.y, bq.y, s);
            s = fmaf(a.z, bq.z, s); s = fmaf(a.w, bq.w, s);
        }
        sd_sh[wave][sd2][gg2][hh2][n] = s;
    }
    __syncthreads();

    // ---- masked softmax + PV + ELU + lane-mean, per column ----
    #pragma unroll
    for (int c = 0; c < 4; ++c) {
        const int gg = c >> 1;
        const int hh = ((c & 1) << 1) + hl;
        float drow[12];
        #pragma unroll
        for (int m = 0; m < 12; ++m) drow[m] = sd_sh[wave][1][gg][hh][m];
        float colacc = 0.f;
        for (int n = 0; n < 12; ++n) {
            float sn = sd_sh[wave][0][gg][hh][n];
            int am = adjm_sh[gg][n];
            float e[12];
            float mx = -1e30f;
            #pragma unroll
            for (int m = 0; m < 12; ++m) {
                float t_ = sn + drow[m];
                t_ = (t_ > 0.f) ? t_ : 0.2f * t_;          // leaky_relu 0.2
                e[m] = ((am >> m) & 1) ? t_ : -1e30f;       // mask
                mx = fmaxf(mx, e[m]);
            }
            float sum = 0.f, pv = 0.f;
            #pragma unroll
            for (int m = 0; m < 12; ++m) {
                float p = __expf(e[m] - mx);                // masked -> 0
                sum += p;
                pv = fmaf(p, acc[c][m], pv);
            }
            float rr = pv / sum;
            rr = (rr > 0.f) ? rr : (__expf(rr) - 1.f);      // ELU
            colacc += rr;
        }
        emb[(size_t)g * 256 + c * 64 + lane] = f2et<ET>(colacc * (1.f / 12.f));
    }
}

// ---------------------------------------------------------------------------
// Kernel 2: GraphSAGE + node pool. One wave per (b,t), lane = output unit.
// ---------------------------------------------------------------------------
template<typename ET>
__global__ __launch_bounds__(256) void sage_kernel(
    const ET* __restrict__ emb, const int* __restrict__ mask,
    const float* __restrict__ W_self, const float* __restrict__ W_neigh,
    const float* __restrict__ b_sage, float* __restrict__ pooled)
{
    __shared__ __align__(16) float x_sh[4][5][256];
    const int tid = threadIdx.x, wave = tid >> 6, lane = tid & 63;
    const int bt = blockIdx.x * 4 + wave;          // 0..20479
    const int b = bt / 5;

    const ET* src = emb + (size_t)bt * 5 * 256;    // [node][f] contiguous for this (b,t)
    float* xf = &x_sh[wave][0][0];
    for (int i = lane; i < 1280; i += 64) xf[i] = et2f<ET>(src[i]);
    __syncthreads();

    float md[4];
    #pragma unroll
    for (int d = 0; d < 4; ++d) md[d] = (float)mask[b * 4 + d];
    const float degs = fmaxf(md[0] + md[1] + md[2] + md[3], 1.f);

    float dS[5], dN[5];
    #pragma unroll
    for (int n = 0; n < 5; ++n) { dS[n] = 0.f; dN[n] = 0.f; }

    for (int f = 0; f < 256; ++f) {
        float ws = W_self[f * 64 + lane];
        float wn = W_neigh[f * 64 + lane];
        #pragma unroll
        for (int n = 0; n < 5; ++n) {
            float xv = x_sh[wave][n][f];
            dS[n] = fmaf(xv, ws, dS[n]);
            dN[n] = fmaf(xv, wn, dN[n]);
        }
    }
    const float bsg = b_sage[lane];
    float agg0 = (md[0] * dN[1] + md[1] * dN[2] + md[2] * dN[3] + md[3] * dN[4]) / degs;
    float p = fmaxf(dS[0] + agg0 + bsg, 0.f);
    #pragma unroll
    for (int d = 0; d < 4; ++d)
        p += fmaxf(dS[d + 1] + md[d] * dN[0] + bsg, 0.f);

    pooled[(size_t)bt * 64 + lane] = p * 0.2f;
}

// ---------------------------------------------------------------------------
// Kernel 3: bidirectional GRU (lanes 0-31 fwd, 32-63 bwd) + output assembly.
// ---------------------------------------------------------------------------
template<typename ET>
__global__ __launch_bounds__(256) void gru_kernel(
    const float* __restrict__ pooled, const ET* __restrict__ emb,
    const float* __restrict__ Wx_f, const float* __restrict__ Wh_f,
    const float* __restrict__ bx_f, const float* __restrict__ bh_f,
    const float* __restrict__ Wx_b, const float* __restrict__ Wh_b,
    const float* __restrict__ bx_b, const float* __restrict__ bh_b,
    float* __restrict__ out)
{
    __shared__ float x_sh[4][5][64];
    __shared__ float h_sh[4][2][32];
    const int tid = threadIdx.x, wave = tid >> 6, lane = tid & 63;
    const int b = blockIdx.x * 4 + wave;

    #pragma unroll
    for (int t = 0; t < 5; ++t) x_sh[wave][t][lane] = pooled[(size_t)(b * 5 + t) * 64 + lane];

    const int j = lane & 31, dir = lane >> 5;
    const float* Wx = dir ? Wx_b : Wx_f;
    const float* Wh = dir ? Wh_b : Wh_f;
    const float* bx = dir ? bx_b : bx_f;
    const float* bh = dir ? bh_b : bh_f;
    const float bxr = bx[j], bxz = bx[32 + j], bxn = bx[64 + j];
    const float bhr = bh[j], bhz = bh[32 + j], bhn = bh[64 + j];
    float h = 0.f;
    __syncthreads();

    for (int s = 0; s < 5; ++s) {
        const int t = dir ? (4 - s) : s;
        h_sh[wave][dir][j] = h;
        __syncthreads();
        float xr = bxr, xz = bxz, xn = bxn;
        for (int f = 0; f < 64; ++f) {
            float xv = x_sh[wave][t][f];
            xr = fmaf(xv, Wx[f * 96 + j], xr);
            xz = fmaf(xv, Wx[f * 96 + 32 + j], xz);
            xn = fmaf(xv, Wx[f * 96 + 64 + j], xn);
        }
        float hr = bhr, hz = bhz, hn = bhn;
        for (int f = 0; f < 32; ++f) {
            float hv = h_sh[wave][dir][f];
            hr = fmaf(hv, Wh[f * 96 + j], hr);
            hz = fmaf(hv, Wh[f * 96 + 32 + j], hz);
            hn = fmaf(hv, Wh[f * 96 + 64 + j], hn);
        }
        float rr = 1.f / (1.f + __expf(-(xr + hr)));
        float zz = 1.f / (1.f + __expf(-(xz + hz)));
        float ni = xn + rr * hn;
        ni = fminf(fmaxf(ni, -15.f), 15.f);
        float e2 = __expf(2.f * ni);
        float nn = (e2 - 1.f) / (e2 + 1.f);
        h = (1.f - zz) * nn + zz * h;
        __syncthreads();
    }

    // network_emb: [256:288]=hf, [288:320]=hb
    out[(size_t)b * 320 + 256 + dir * 32 + j] = h;
    // self_emb[:, t=4, :] lives at emb row b*25 + 4*5 + 0 = (b*5+4)*5
    const ET* se = emb + (size_t)((b * 5 + 4) * 5) * 256;
    #pragma unroll
    for (int c = 0; c < 4; ++c)
        out[(size_t)b * 320 + c * 64 + lane] = et2f<ET>(se[c * 64 + lane]);
}

// ---------------------------------------------------------------------------
template<typename ET>
static void run_pipeline(void* const* d_in, float* out, void* d_ws, hipStream_t stream) {
    const float* self_feat = (const float*)d_in[0];
    const float* nbr_feat  = (const float*)d_in[1];
    const float* W_in   = (const float*)d_in[2];
    const float* b_in_  = (const float*)d_in[3];
    const float* ln_g   = (const float*)d_in[4];
    const float* ln_b   = (const float*)d_in[5];
    const float* W_coop = (const float*)d_in[6];
    const float* as_c   = (const float*)d_in[7];
    const float* ad_c   = (const float*)d_in[8];
    const float* W_conf = (const float*)d_in[9];
    const float* as_f   = (const float*)d_in[10];
    const float* ad_f   = (const float*)d_in[11];
    const float* W_self = (const float*)d_in[12];
    const float* W_neigh= (const float*)d_in[13];
    const float* b_sage = (const float*)d_in[14];
    const float* Wx_f   = (const float*)d_in[15];
    const float* Wh_f   = (const float*)d_in[16];
    const float* bx_f   = (const float*)d_in[17];
    const float* bh_f   = (const float*)d_in[18];
    const float* Wx_b   = (const float*)d_in[19];
    const float* Wh_b   = (const float*)d_in[20];
    const float* bx_b   = (const float*)d_in[21];
    const float* bh_b   = (const float*)d_in[22];
    const float* adj_coop = (const float*)d_in[23];
    const float* adj_conf = (const float*)d_in[24];
    const int*   mask   = (const int*)d_in[25];

    ET* emb = (ET*)d_ws;
    float* pooled = (float*)((char*)d_ws + (size_t)GTOT * 256 * sizeof(ET));

    gat_kernel<ET><<<GTOT / 4, 256, 0, stream>>>(self_feat, nbr_feat, W_in, b_in_, ln_g, ln_b,
        W_coop, as_c, ad_c, W_conf, as_f, ad_f, adj_coop, adj_conf, emb);
    sage_kernel<ET><<<(BB * TT) / 4, 256, 0, stream>>>(emb, mask, W_self, W_neigh, b_sage, pooled);
    gru_kernel<ET><<<BB / 4, 256, 0, stream>>>(pooled, emb,
        Wx_f, Wh_f, bx_f, bh_f, Wx_b, Wh_b, bx_b, bh_b, out);
}

extern "C" void kernel_launch(void* const* d_in, const int* in_sizes, int n_in,
                              void* d_out, int out_size, void* d_ws, size_t ws_size,
                              hipStream_t stream) {
    (void)in_sizes; (void)n_in; (void)out_size;
    float* out = (float*)d_out;
    const size_t need_f32 = (size_t)GTOT * 256 * sizeof(float) + (size_t)BB * TT * 64 * sizeof(float);
    if (ws_size >= need_f32) {
        run_pipeline<float>(d_in, out, d_ws, stream);
    } else {
        run_pipeline<__hip_bfloat16>(d_in, out, d_ws, stream);
    }
}

// Round 3
// 621.637 us; speedup vs baseline: 3.7290x; 3.7290x over previous
//
#include <hip/hip_runtime.h>
#include <hip/hip_bf16.h>

#define BB 4096
#define KK 4
#define TT 5
#define GTOT (BB * TT * 5)   // 102400 graphs; emb row = b*25 + t*5 + node
#define BFRAG_ELEMS 17408    // 17 tiles * 2 ksteps * 64 lanes * 8 bf16
#define BFRAG_BYTES 36864    // padded to 4KB multiple

typedef __bf16 bf16x8_t __attribute__((ext_vector_type(8)));
typedef short  s16x4_t  __attribute__((ext_vector_type(4)));
typedef float  f32x4_t  __attribute__((ext_vector_type(4)));

template<typename ET> __device__ __forceinline__ float et2f(ET v);
template<> __device__ __forceinline__ float et2f<float>(float v) { return v; }
template<> __device__ __forceinline__ float et2f<__hip_bfloat16>(__hip_bfloat16 v) { return __bfloat162float(v); }
template<typename ET> __device__ __forceinline__ ET f2et(float v);
template<> __device__ __forceinline__ float f2et<float>(float v) { return v; }
template<> __device__ __forceinline__ __hip_bfloat16 f2et<__hip_bfloat16>(float v) { return __float2bfloat16(v); }

static __device__ __forceinline__ unsigned short f2bf(float v) {
    return __builtin_bit_cast(unsigned short, __float2bfloat16(v));
}

// ---------------------------------------------------------------------------
// Prep: build bf16 B-fragments for the per-graph GEMM.
// B[k][n], k in [0,64): n<256 -> W[pair][k][o]; n in [256,264): u_src[pair][k];
// n in [264,272): u_dst[pair][k].  Fragment layout: idx = ((it*2+ks)*64+l)*8+j
// holds B[ks*32 + (l>>4)*8 + j][it*16 + (l&15)].
// ---------------------------------------------------------------------------
__global__ void prep_kernel(
    const float* __restrict__ W_coop, const float* __restrict__ as_c, const float* __restrict__ ad_c,
    const float* __restrict__ W_conf, const float* __restrict__ as_f, const float* __restrict__ ad_f,
    unsigned short* __restrict__ bfrag)
{
    for (int idx = threadIdx.x; idx < BFRAG_ELEMS; idx += 256) {
        int j = idx & 7, l = (idx >> 3) & 63;
        int rest = idx >> 9, ks = rest & 1, it = rest >> 1;
        int k = ks * 32 + ((l >> 4) << 3) + j;
        int n = it * 16 + (l & 15);
        float val;
        if (n < 256) {
            int p = n >> 5, o = n & 31, head = p & 3;
            const float* W = (p >> 2) ? W_conf : W_coop;
            val = W[(head * 64 + k) * 32 + o];
        } else {
            int c = n - 256, sd = c >> 3, p = c & 7;
            int gat = p >> 2, head = p & 3;
            const float* W = gat ? W_conf : W_coop;
            const float* a = sd ? (gat ? ad_f : ad_c) : (gat ? as_f : as_c);
            float s = 0.f;
            for (int o = 0; o < 32; ++o) s = fmaf(W[(head * 64 + k) * 32 + o], a[head * 32 + o], s);
            val = s;
        }
        bfrag[idx] = f2bf(val);
    }
}

// ---------------------------------------------------------------------------
// Kernel 1: GAT encoder, MFMA edition. One wave per graph, 4 waves/block.
// ---------------------------------------------------------------------------
template<typename ET>
__global__ __launch_bounds__(256) void gat_kernel(
    const float* __restrict__ self_feat, const float* __restrict__ nbr_feat,
    const float* __restrict__ W_in, const float* __restrict__ b_in,
    const float* __restrict__ ln_g, const float* __restrict__ ln_b,
    const float* __restrict__ adj_coop, const float* __restrict__ adj_conf,
    const unsigned short* __restrict__ bfrag,
    ET* __restrict__ emb)
{
    __shared__ unsigned short Bf_sh[BFRAG_ELEMS];          // 34816 B, block-shared
    __shared__ unsigned short h_sh[4][16][64];             // 8192 B, bf16, XOR-swizzled cols
    __shared__ float          sc_sh[4][16][16];            // 4096 B  [col(0-7 src,8-15 dst)][node]
    __shared__ unsigned short attn_sh[4][8][16][16];       // 16384 B bf16 attn rows (n, m padded to 16)
    __shared__ int            adjm_sh[2][12];

    const int tid = threadIdx.x, wave = tid >> 6, lane = tid & 63;
    const int lg = lane >> 4;

    // ---- cooperative loads: B fragments + adjacency masks ----
    {
        const uint2* src = (const uint2*)bfrag;
        uint2* dst = (uint2*)Bf_sh;
        #pragma unroll
        for (int i = 0; i < 17; ++i) dst[tid + 256 * i] = src[tid + 256 * i];
    }
    if (tid < 24) {
        int gat = tid / 12, n = tid % 12;
        const float* adj = gat ? adj_conf : adj_coop;
        int m = 0;
        for (int c = 0; c < 12; ++c) if (adj[n * 12 + c] > 0.f) m |= (1 << c);
        adjm_sh[gat][n] = m;
    }
    __syncthreads();

    // ---- graph decode ----
    const int g = blockIdx.x * 4 + wave;
    const int b = g / 25, r_ = g % 25, t = r_ / 5, node = r_ % 5;
    const float* x = (node == 0) ? (self_feat + (size_t)(b * 5 + t) * 48)
                                 : (nbr_feat + (size_t)((b * 4 + (node - 1)) * 5 + t) * 48);

    // ---- h = x@W_in + b ; LayerNorm ; ReLU ; -> LDS bf16 (lane = feature) ----
    const float w0 = W_in[lane], w1 = W_in[64 + lane], w2 = W_in[128 + lane], w3 = W_in[192 + lane];
    const float bb_ = b_in[lane], lgn = ln_g[lane], lbn = ln_b[lane];
    #pragma unroll
    for (int n = 0; n < 12; ++n) {
        float4 xv = *(const float4*)(x + n * 4);
        float hv = fmaf(xv.x, w0, fmaf(xv.y, w1, fmaf(xv.z, w2, fmaf(xv.w, w3, bb_))));
        float s = hv, s2 = hv * hv;
        #pragma unroll
        for (int mm = 1; mm < 64; mm <<= 1) {
            s  += __shfl_xor(s, mm, 64);
            s2 += __shfl_xor(s2, mm, 64);
        }
        float mu  = s * (1.f / 64.f);
        float var = s2 * (1.f / 64.f) - mu * mu;
        float vv  = fmaxf((hv - mu) * rsqrtf(var + 1e-5f) * lgn + lbn, 0.f);
        h_sh[wave][n][lane ^ ((n & 7) << 3)] = f2bf(vv);
    }
    if (lane < 32) ((uint4*)&h_sh[wave][12][0])[lane] = make_uint4(0u, 0u, 0u, 0u);
    __asm__ volatile("" ::: "memory");   // keep LDS write->read order (same-wave DS is in-order)

    // ---- main GEMM: C[16 nodes x 272] = h[16x64] @ B[64x272], 17 tiles x 2 ksteps ----
    bf16x8_t afrag[2];
    {
        const int m = lane & 15;
        #pragma unroll
        for (int ks = 0; ks < 2; ++ks) {
            int f0 = (ks * 32 + lg * 8) ^ ((m & 7) << 3);
            afrag[ks] = *(const bf16x8_t*)&h_sh[wave][m][f0];
        }
    }
    f32x4_t acc[17];
    #pragma unroll
    for (int it = 0; it < 17; ++it) acc[it] = (f32x4_t){0.f, 0.f, 0.f, 0.f};
    #pragma unroll
    for (int it = 0; it < 17; ++it) {
        #pragma unroll
        for (int ks = 0; ks < 2; ++ks) {
            bf16x8_t bfr = *(const bf16x8_t*)&Bf_sh[((it * 2 + ks) * 64 + lane) * 8];
            acc[it] = __builtin_amdgcn_mfma_f32_16x16x32_bf16(afrag[ks], bfr, acc[it], 0, 0, 0);
        }
    }

    // ---- tile 16 = attention scores: sc[col][node] (col 0-7 src, 8-15 dst) ----
    {
        const int col = lane & 15;
        #pragma unroll
        for (int r = 0; r < 4; ++r) sc_sh[wave][col][lg * 4 + r] = acc[16][r];
    }
    __asm__ volatile("" ::: "memory");

    // ---- softmax, computed once: 128 (pair,row) tasks over 2 passes ----
    #pragma unroll
    for (int jj = 0; jj < 2; ++jj) {
        int v = jj * 64 + lane;
        int p = v >> 4, n = v & 15;
        uint2* arow = (uint2*)&attn_sh[wave][p][n][0];
        if (n < 12) {
            float ssrc = sc_sh[wave][p][n];
            const float* dm = &sc_sh[wave][8 + p][0];
            int am = adjm_sh[p >> 2][n];
            float e[12]; float mx = -1e30f;
            #pragma unroll
            for (int m = 0; m < 12; ++m) {
                float tv = ssrc + dm[m];
                tv = fmaxf(tv, 0.2f * tv);                 // leaky_relu(0.2)
                e[m] = ((am >> m) & 1) ? tv : -1e30f;
                mx = fmaxf(mx, e[m]);
            }
            float ssum = 0.f; float pr[12];
            #pragma unroll
            for (int m = 0; m < 12; ++m) { pr[m] = __expf(e[m] - mx); ssum += pr[m]; }
            float inv = 1.f / ssum;
            unsigned int u[12];
            #pragma unroll
            for (int m = 0; m < 12; ++m) u[m] = (unsigned int)f2bf(pr[m] * inv);
            arow[0] = make_uint2(u[0] | (u[1] << 16), u[2]  | (u[3]  << 16));
            arow[1] = make_uint2(u[4] | (u[5] << 16), u[6]  | (u[7]  << 16));
            arow[2] = make_uint2(u[8] | (u[9] << 16), u[10] | (u[11] << 16));
            arow[3] = make_uint2(0u, 0u);
        } else {
            arow[0] = make_uint2(0u, 0u); arow[1] = make_uint2(0u, 0u);
            arow[2] = make_uint2(0u, 0u); arow[3] = make_uint2(0u, 0u);
        }
    }
    __asm__ volatile("" ::: "memory");

    // ---- PV via 16x16x16 MFMA: B-frag IS the main-GEMM C-register block ----
    const f32x4_t zero4 = (f32x4_t){0.f, 0.f, 0.f, 0.f};
    #pragma unroll
    for (int p = 0; p < 8; ++p) {
        s16x4_t afr = *(const s16x4_t*)&attn_sh[wave][p][lane & 15][lg * 4];
        #pragma unroll
        for (int tt = 0; tt < 2; ++tt) {
            const int it = p * 2 + tt;
            s16x4_t bfr;
            bfr[0] = (short)f2bf(acc[it][0]);
            bfr[1] = (short)f2bf(acc[it][1]);
            bfr[2] = (short)f2bf(acc[it][2]);
            bfr[3] = (short)f2bf(acc[it][3]);
            f32x4_t pv = __builtin_amdgcn_mfma_f32_16x16x16bf16_1k(afr, bfr, zero4, 0, 0, 0);
            float ss = 0.f;
            #pragma unroll
            for (int r = 0; r < 4; ++r) {
                float xv = pv[r];
                xv = (xv > 0.f) ? xv : (__expf(xv) - 1.f);  // ELU (rows 12-15 are exact 0)
                ss += xv;
            }
            ss += __shfl_xor(ss, 16, 64);
            ss += __shfl_xor(ss, 32, 64);
            if (lane < 16)
                emb[(size_t)g * 256 + p * 32 + tt * 16 + lane] = f2et<ET>(ss * (1.f / 12.f));
        }
    }
}

// ---------------------------------------------------------------------------
// Kernel 2: GraphSAGE + node pool. One wave per (b,t), lane = output unit.
// ---------------------------------------------------------------------------
template<typename ET>
__global__ __launch_bounds__(256) void sage_kernel(
    const ET* __restrict__ emb, const int* __restrict__ mask,
    const float* __restrict__ W_self, const float* __restrict__ W_neigh,
    const float* __restrict__ b_sage, float* __restrict__ pooled)
{
    __shared__ __align__(16) float x_sh[4][5][256];
    const int tid = threadIdx.x, wave = tid >> 6, lane = tid & 63;
    const int bt = blockIdx.x * 4 + wave;
    const int b = bt / 5;

    const ET* src = emb + (size_t)bt * 5 * 256;
    float* xf = &x_sh[wave][0][0];
    for (int i = lane; i < 1280; i += 64) xf[i] = et2f<ET>(src[i]);
    __syncthreads();

    float md[4];
    #pragma unroll
    for (int d = 0; d < 4; ++d) md[d] = (float)mask[b * 4 + d];
    const float degs = fmaxf(md[0] + md[1] + md[2] + md[3], 1.f);

    float dS[5], dN[5];
    #pragma unroll
    for (int n = 0; n < 5; ++n) { dS[n] = 0.f; dN[n] = 0.f; }

    for (int f = 0; f < 256; ++f) {
        float ws = W_self[f * 64 + lane];
        float wn = W_neigh[f * 64 + lane];
        #pragma unroll
        for (int n = 0; n < 5; ++n) {
            float xv = x_sh[wave][n][f];
            dS[n] = fmaf(xv, ws, dS[n]);
            dN[n] = fmaf(xv, wn, dN[n]);
        }
    }
    const float bsg = b_sage[lane];
    float agg0 = (md[0] * dN[1] + md[1] * dN[2] + md[2] * dN[3] + md[3] * dN[4]) / degs;
    float p = fmaxf(dS[0] + agg0 + bsg, 0.f);
    #pragma unroll
    for (int d = 0; d < 4; ++d)
        p += fmaxf(dS[d + 1] + md[d] * dN[0] + bsg, 0.f);

    pooled[(size_t)bt * 64 + lane] = p * 0.2f;
}

// ---------------------------------------------------------------------------
// Kernel 3: bidirectional GRU (lanes 0-31 fwd, 32-63 bwd) + output assembly.
// ---------------------------------------------------------------------------
template<typename ET>
__global__ __launch_bounds__(256) void gru_kernel(
    const float* __restrict__ pooled, const ET* __restrict__ emb,
    const float* __restrict__ Wx_f, const float* __restrict__ Wh_f,
    const float* __restrict__ bx_f, const float* __restrict__ bh_f,
    const float* __restrict__ Wx_b, const float* __restrict__ Wh_b,
    const float* __restrict__ bx_b, const float* __restrict__ bh_b,
    float* __restrict__ out)
{
    __shared__ float x_sh[4][5][64];
    __shared__ float h_sh[4][2][32];
    const int tid = threadIdx.x, wave = tid >> 6, lane = tid & 63;
    const int b = blockIdx.x * 4 + wave;

    #pragma unroll
    for (int t = 0; t < 5; ++t) x_sh[wave][t][lane] = pooled[(size_t)(b * 5 + t) * 64 + lane];

    const int j = lane & 31, dir = lane >> 5;
    const float* Wx = dir ? Wx_b : Wx_f;
    const float* Wh = dir ? Wh_b : Wh_f;
    const float* bx = dir ? bx_b : bx_f;
    const float* bh = dir ? bh_b : bh_f;
    const float bxr = bx[j], bxz = bx[32 + j], bxn = bx[64 + j];
    const float bhr = bh[j], bhz = bh[32 + j], bhn = bh[64 + j];
    float h = 0.f;
    __syncthreads();

    for (int s = 0; s < 5; ++s) {
        const int t = dir ? (4 - s) : s;
        h_sh[wave][dir][j] = h;
        __syncthreads();
        float xr = bxr, xz = bxz, xn = bxn;
        for (int f = 0; f < 64; ++f) {
            float xv = x_sh[wave][t][f];
            xr = fmaf(xv, Wx[f * 96 + j], xr);
            xz = fmaf(xv, Wx[f * 96 + 32 + j], xz);
            xn = fmaf(xv, Wx[f * 96 + 64 + j], xn);
        }
        float hr = bhr, hz = bhz, hn = bhn;
        for (int f = 0; f < 32; ++f) {
            float hv = h_sh[wave][dir][f];
            hr = fmaf(hv, Wh[f * 96 + j], hr);
            hz = fmaf(hv, Wh[f * 96 + 32 + j], hz);
            hn = fmaf(hv, Wh[f * 96 + 64 + j], hn);
        }
        float rr = 1.f / (1.f + __expf(-(xr + hr)));
        float zz = 1.f / (1.f + __expf(-(xz + hz)));
        float ni = xn + rr * hn;
        ni = fminf(fmaxf(ni, -15.f), 15.f);
        float e2 = __expf(2.f * ni);
        float nn = (e2 - 1.f) / (e2 + 1.f);
        h = (1.f - zz) * nn + zz * h;
        __syncthreads();
    }

    out[(size_t)b * 320 + 256 + dir * 32 + j] = h;
    const ET* se = emb + (size_t)((b * 5 + 4) * 5) * 256;
    #pragma unroll
    for (int c = 0; c < 4; ++c)
        out[(size_t)b * 320 + c * 64 + lane] = et2f<ET>(se[c * 64 + lane]);
}

// ---------------------------------------------------------------------------
template<typename ET>
static void run_pipeline(void* const* d_in, float* out, void* d_ws, hipStream_t stream) {
    const float* self_feat = (const float*)d_in[0];
    const float* nbr_feat  = (const float*)d_in[1];
    const float* W_in   = (const float*)d_in[2];
    const float* b_in_  = (const float*)d_in[3];
    const float* ln_g   = (const float*)d_in[4];
    const float* ln_b   = (const float*)d_in[5];
    const float* W_coop = (const float*)d_in[6];
    const float* as_c   = (const float*)d_in[7];
    const float* ad_c   = (const float*)d_in[8];
    const float* W_conf = (const float*)d_in[9];
    const float* as_f   = (const float*)d_in[10];
    const float* ad_f   = (const float*)d_in[11];
    const float* W_self = (const float*)d_in[12];
    const float* W_neigh= (const float*)d_in[13];
    const float* b_sage = (const float*)d_in[14];
    const float* Wx_f   = (const float*)d_in[15];
    const float* Wh_f   = (const float*)d_in[16];
    const float* bx_f   = (const float*)d_in[17];
    const float* bh_f   = (const float*)d_in[18];
    const float* Wx_b   = (const float*)d_in[19];
    const float* Wh_b   = (const float*)d_in[20];
    const float* bx_b   = (const float*)d_in[21];
    const float* bh_b   = (const float*)d_in[22];
    const float* adj_coop = (const float*)d_in[23];
    const float* adj_conf = (const float*)d_in[24];
    const int*   mask   = (const int*)d_in[25];

    unsigned short* bfrag = (unsigned short*)d_ws;
    ET* emb = (ET*)((char*)d_ws + BFRAG_BYTES);
    float* pooled = (float*)((char*)d_ws + BFRAG_BYTES + (size_t)GTOT * 256 * sizeof(ET));

    prep_kernel<<<1, 256, 0, stream>>>(W_coop, as_c, ad_c, W_conf, as_f, ad_f, bfrag);
    gat_kernel<ET><<<GTOT / 4, 256, 0, stream>>>(self_feat, nbr_feat, W_in, b_in_, ln_g, ln_b,
        adj_coop, adj_conf, bfrag, emb);
    sage_kernel<ET><<<(BB * TT) / 4, 256, 0, stream>>>(emb, mask, W_self, W_neigh, b_sage, pooled);
    gru_kernel<ET><<<BB / 4, 256, 0, stream>>>(pooled, emb,
        Wx_f, Wh_f, bx_f, bh_f, Wx_b, Wh_b, bx_b, bh_b, out);
}

extern "C" void kernel_launch(void* const* d_in, const int* in_sizes, int n_in,
                              void* d_out, int out_size, void* d_ws, size_t ws_size,
                              hipStream_t stream) {
    (void)in_sizes; (void)n_in; (void)out_size;
    float* out = (float*)d_out;
    const size_t need_f32 = BFRAG_BYTES + (size_t)GTOT * 256 * sizeof(float)
                          + (size_t)BB * TT * 64 * sizeof(float);
    if (ws_size >= need_f32) {
        run_pipeline<float>(d_in, out, d_ws, stream);
    } else {
        run_pipeline<__hip_bfloat16>(d_in, out, d_ws, stream);
    }
}

// Round 4
// 434.056 us; speedup vs baseline: 5.3405x; 1.4322x over previous
//
#include <hip/hip_runtime.h>
#include <hip/hip_bf16.h>

#define BB 4096
#define TT 5
#define GTOT (BB * TT * 5)        // 102400 graphs; emb row = b*25 + t*5 + node

// workspace byte offsets (total ~57.8 MB; bf16 emb everywhere)
#define OFF_BFRAG  0              // 17408 bf16 = 34816 B (gat B-fragments)
#define OFF_ADJ    36864          // 32 ints (adj masks [2][16])
#define OFF_SFRAG  40960          // 32768 bf16 = 65536 B (sage B-fragments)
#define OFF_EMB    106496         // 102400*256 bf16 = 52428800 B
#define OFF_POOLED 52535296ULL    // 20480*64 f32 = 5242880 B

typedef __bf16 bf16x8_t __attribute__((ext_vector_type(8)));
typedef short  s16x4_t  __attribute__((ext_vector_type(4)));
typedef float  f32x4_t  __attribute__((ext_vector_type(4)));

static __device__ __forceinline__ unsigned short f2bf(float v) {
    return __builtin_bit_cast(unsigned short, __float2bfloat16(v));
}
static __device__ __forceinline__ float bf2f(unsigned short u) {
    return __builtin_bit_cast(float, ((unsigned int)u) << 16);
}

// ---------------------------------------------------------------------------
// Prep: B-fragments for gat GEMM (17 tiles x 2 ksteps), sage GEMM
// (8 tiles x 8 ksteps), and adjacency bitmasks.
// gat  B[k][n]: n<256 -> W[pair p=n>>5][k][o=n&31]; n in [256,264): u_src[p][k];
//               n in [264,272): u_dst[p][k].  idx = ((it*2+ks)*64+l)*8+j,
//               k = ks*32+(l>>4)*8+j, n = it*16+(l&15).
// sage B[k][n]: n<64 -> W_self[k][n]; else W_neigh[k][n-64]. idx=((nt*8+ks)*64+l)*8+j.
// ---------------------------------------------------------------------------
__global__ void prep_kernel(
    const float* __restrict__ W_coop, const float* __restrict__ as_c, const float* __restrict__ ad_c,
    const float* __restrict__ W_conf, const float* __restrict__ as_f, const float* __restrict__ ad_f,
    const float* __restrict__ W_self, const float* __restrict__ W_neigh,
    const float* __restrict__ adj_coop, const float* __restrict__ adj_conf,
    unsigned short* __restrict__ bfrag, int* __restrict__ adjm_g,
    unsigned short* __restrict__ sfrag)
{
    const int gtid = blockIdx.x * 256 + threadIdx.x;
    const int gstride = gridDim.x * 256;

    for (int idx = gtid; idx < 17408; idx += gstride) {
        int j = idx & 7, l = (idx >> 3) & 63;
        int rest = idx >> 9, ks = rest & 1, it = rest >> 1;
        int k = ks * 32 + ((l >> 4) << 3) + j;
        int n = it * 16 + (l & 15);
        float val;
        if (n < 256) {
            int p = n >> 5, o = n & 31, head = p & 3;
            const float* W = (p >> 2) ? W_conf : W_coop;
            val = W[(head * 64 + k) * 32 + o];
        } else {
            int c = n - 256, sd = c >> 3, p = c & 7;
            int gat = p >> 2, head = p & 3;
            const float* W = gat ? W_conf : W_coop;
            const float* a = sd ? (gat ? ad_f : ad_c) : (gat ? as_f : as_c);
            float s = 0.f;
            for (int o = 0; o < 32; ++o) s = fmaf(W[(head * 64 + k) * 32 + o], a[head * 32 + o], s);
            val = s;
        }
        bfrag[idx] = f2bf(val);
    }

    for (int idx = gtid; idx < 32768; idx += gstride) {
        int j = idx & 7, l = (idx >> 3) & 63;
        int rest = idx >> 9, ks = rest & 7, nt = rest >> 3;
        int k = ks * 32 + ((l >> 4) << 3) + j;
        int n = nt * 16 + (l & 15);
        float v = (n < 64) ? W_self[k * 64 + n] : W_neigh[k * 64 + (n - 64)];
        sfrag[idx] = f2bf(v);
    }

    if (gtid < 32) {
        int gat = gtid >> 4, n = gtid & 15;
        int m = 0;
        if (n < 12) {
            const float* adj = gat ? adj_conf : adj_coop;
            for (int c = 0; c < 12; ++c) if (adj[n * 12 + c] > 0.f) m |= (1 << c);
        }
        adjm_g[gtid] = m;
    }
}

// ---------------------------------------------------------------------------
// Kernel 1: GAT encoder. One wave per graph, 4 independent waves/block,
// NO barriers (all LDS is per-wave). B-fragments read from global (L1-hot).
// ---------------------------------------------------------------------------
__global__ __launch_bounds__(256) void gat_kernel(
    const float* __restrict__ self_feat, const float* __restrict__ nbr_feat,
    const float* __restrict__ W_in, const float* __restrict__ b_in,
    const float* __restrict__ ln_g, const float* __restrict__ ln_b,
    const unsigned short* __restrict__ bfrag, const int* __restrict__ adjm_g,
    unsigned short* __restrict__ emb)
{
    __shared__ unsigned short h_sh[4][16][64];        // 8192 B, XOR-swizzled 16B groups
    __shared__ float          sc_sh[4][16][12];       // 3072 B  [col(0-7 src,8-15 dst)][node]
    __shared__ unsigned short attn_sh[4][8][16][20];  // 20480 B, rows padded to 40 B (conflict-free)

    const int tid = threadIdx.x, wave = tid >> 6, lane = tid & 63;
    const int lg = lane >> 4;

    // ---- graph decode ----
    const int g = blockIdx.x * 4 + wave;
    const int b = g / 25, r_ = g % 25, t = r_ / 5, node = r_ % 5;
    const float* x = (node == 0) ? (self_feat + (size_t)(b * 5 + t) * 48)
                                 : (nbr_feat + (size_t)((b * 4 + (node - 1)) * 5 + t) * 48);

    // ---- h = x@W_in + b ; LayerNorm ; ReLU ; -> LDS bf16 (lane = feature) ----
    const float w0 = W_in[lane], w1 = W_in[64 + lane], w2 = W_in[128 + lane], w3 = W_in[192 + lane];
    const float bb_ = b_in[lane], lgn = ln_g[lane], lbn = ln_b[lane];
    #pragma unroll
    for (int n = 0; n < 12; ++n) {
        float4 xv = *(const float4*)(x + n * 4);
        float hv = fmaf(xv.x, w0, fmaf(xv.y, w1, fmaf(xv.z, w2, fmaf(xv.w, w3, bb_))));
        float s = hv, s2 = hv * hv;
        #pragma unroll
        for (int mm = 1; mm < 64; mm <<= 1) {
            s  += __shfl_xor(s, mm, 64);
            s2 += __shfl_xor(s2, mm, 64);
        }
        float mu  = s * (1.f / 64.f);
        float var = s2 * (1.f / 64.f) - mu * mu;
        float vv  = fmaxf((hv - mu) * rsqrtf(var + 1e-5f) * lgn + lbn, 0.f);
        h_sh[wave][n][lane ^ ((n & 7) << 3)] = f2bf(vv);
    }
    if (lane < 32) {
        uint4 z = make_uint4(0u, 0u, 0u, 0u);
        ((uint4*)&h_sh[wave][12][0])[lane] = z;       // zero pad rows 12-15
    }
    __asm__ volatile("" ::: "memory");                // same-wave LDS write->read order

    // ---- main GEMM: C[16 x 272] = h[16x64] @ B[64x272]; B streamed from global ----
    bf16x8_t afrag[2];
    {
        const int m = lane & 15;
        #pragma unroll
        for (int ks = 0; ks < 2; ++ks) {
            int f0 = (ks * 32 + lg * 8) ^ ((m & 7) << 3);
            afrag[ks] = *(const bf16x8_t*)&h_sh[wave][m][f0];
        }
    }
    f32x4_t acc[17];
    #pragma unroll
    for (int it = 0; it < 17; ++it) acc[it] = (f32x4_t){0.f, 0.f, 0.f, 0.f};
    #pragma unroll
    for (int it = 0; it < 17; ++it) {
        #pragma unroll
        for (int ks = 0; ks < 2; ++ks) {
            bf16x8_t bfr = *(const bf16x8_t*)&bfrag[(size_t)((it * 2 + ks) * 64 + lane) * 8];
            acc[it] = __builtin_amdgcn_mfma_f32_16x16x32_bf16(afrag[ks], bfr, acc[it], 0, 0, 0);
        }
    }

    // ---- tile 16 = attention scores ----
    {
        const int col = lane & 15;
        if (lg < 3) {
            #pragma unroll
            for (int r = 0; r < 4; ++r) sc_sh[wave][col][lg * 4 + r] = acc[16][r];
        }
    }
    __asm__ volatile("" ::: "memory");

    // ---- softmax once per (pair,row): 128 tasks / 2 passes; no max-sub (scores tiny) ----
    #pragma unroll
    for (int jj = 0; jj < 2; ++jj) {
        int v = jj * 64 + lane;
        int p = v >> 4, n = v & 15;
        uint2* arow = (uint2*)&attn_sh[wave][p][n][0];
        if (n < 12) {
            float ssrc = sc_sh[wave][p][n];
            float4 d0 = *(const float4*)&sc_sh[wave][8 + p][0];
            float4 d1 = *(const float4*)&sc_sh[wave][8 + p][4];
            float4 d2 = *(const float4*)&sc_sh[wave][8 + p][8];
            float dm[12] = {d0.x, d0.y, d0.z, d0.w, d1.x, d1.y, d1.z, d1.w, d2.x, d2.y, d2.z, d2.w};
            int am = adjm_g[(p >> 2) * 16 + n];
            float pr[12]; float ssum = 0.f;
            #pragma unroll
            for (int m = 0; m < 12; ++m) {
                float tv = ssrc + dm[m];
                tv = fmaxf(tv, 0.2f * tv);                 // leaky_relu(0.2)
                float pp = ((am >> m) & 1) ? __expf(tv) : 0.f;
                ssum += pp; pr[m] = pp;
            }
            float inv = 1.f / ssum;
            unsigned int u[12];
            #pragma unroll
            for (int m = 0; m < 12; ++m) u[m] = (unsigned int)f2bf(pr[m] * inv);
            arow[0] = make_uint2(u[0] | (u[1] << 16), u[2]  | (u[3]  << 16));
            arow[1] = make_uint2(u[4] | (u[5] << 16), u[6]  | (u[7]  << 16));
            arow[2] = make_uint2(u[8] | (u[9] << 16), u[10] | (u[11] << 16));
            arow[3] = make_uint2(0u, 0u);                  // cols 12-15 (read by PV)
        } else {
            arow[0] = make_uint2(0u, 0u); arow[1] = make_uint2(0u, 0u);
            arow[2] = make_uint2(0u, 0u); arow[3] = make_uint2(0u, 0u);
        }
    }
    __asm__ volatile("" ::: "memory");

    // ---- PV via 16x16x16 MFMA: B-frag IS the main-GEMM C-register block ----
    const f32x4_t zero4 = (f32x4_t){0.f, 0.f, 0.f, 0.f};
    #pragma unroll
    for (int p = 0; p < 8; ++p) {
        s16x4_t afr = *(const s16x4_t*)&attn_sh[wave][p][lane & 15][lg << 2];
        #pragma unroll
        for (int tt = 0; tt < 2; ++tt) {
            const int it = p * 2 + tt;
            s16x4_t bfr;
            bfr[0] = (short)f2bf(acc[it][0]);
            bfr[1] = (short)f2bf(acc[it][1]);
            bfr[2] = (short)f2bf(acc[it][2]);
            bfr[3] = (short)f2bf(acc[it][3]);
            f32x4_t pv = __builtin_amdgcn_mfma_f32_16x16x16bf16_1k(afr, bfr, zero4, 0, 0, 0);
            float ss = 0.f;
            #pragma unroll
            for (int r = 0; r < 4; ++r) {
                float xv = pv[r];
                xv = (xv > 0.f) ? xv : (__expf(xv) - 1.f);  // ELU (pad rows contribute 0)
                ss += xv;
            }
            ss += __shfl_xor(ss, 16, 64);
            ss += __shfl_xor(ss, 32, 64);
            if (lane < 16)
                emb[(size_t)g * 256 + p * 32 + tt * 16 + lane] = f2bf(ss * (1.f / 12.f));
        }
    }
}

// ---------------------------------------------------------------------------
// Kernel 2: GraphSAGE via MFMA. One wave per (b,t): Y[16x128] = X[16x256]@Wsn,
// A-frags loaded directly from emb in fragment layout; combine in-wave.
// ---------------------------------------------------------------------------
__global__ __launch_bounds__(256) void sage_kernel(
    const unsigned short* __restrict__ emb, const int* __restrict__ mask,
    const unsigned short* __restrict__ sfrag, const float* __restrict__ b_sage,
    float* __restrict__ pooled)
{
    __shared__ float y_sh[4][5][128];                 // 10240 B
    const int tid = threadIdx.x, wave = tid >> 6, lane = tid & 63;
    const int bt = blockIdx.x * 4 + wave;             // 0..20479
    const int b = bt / 5;
    const int lg = lane >> 4, row = lane & 15;

    bf16x8_t afr[8];
    if (row < 5) {
        const unsigned short* base = emb + (size_t)(bt * 5 + row) * 256 + lg * 8;
        #pragma unroll
        for (int ks = 0; ks < 8; ++ks) afr[ks] = *(const bf16x8_t*)(base + ks * 32);
    } else {
        #pragma unroll
        for (int ks = 0; ks < 8; ++ks) {
            uint4 z = make_uint4(0u, 0u, 0u, 0u);
            afr[ks] = __builtin_bit_cast(bf16x8_t, z);
        }
    }

    #pragma unroll
    for (int nt = 0; nt < 8; ++nt) {
        f32x4_t acc = (f32x4_t){0.f, 0.f, 0.f, 0.f};
        #pragma unroll
        for (int ks = 0; ks < 8; ++ks) {
            bf16x8_t bfr = *(const bf16x8_t*)&sfrag[(size_t)((nt * 8 + ks) * 64 + lane) * 8];
            acc = __builtin_amdgcn_mfma_f32_16x16x32_bf16(afr[ks], bfr, acc, 0, 0, 0);
        }
        #pragma unroll
        for (int r = 0; r < 4; ++r) {
            int rw = lg * 4 + r;
            if (rw < 5) y_sh[wave][rw][nt * 16 + row] = acc[r];
        }
    }
    __asm__ volatile("" ::: "memory");

    float md[4];
    #pragma unroll
    for (int d = 0; d < 4; ++d) md[d] = (float)mask[b * 4 + d];
    const float degs = fmaxf(md[0] + md[1] + md[2] + md[3], 1.f);

    float dS[5], dN[5];
    #pragma unroll
    for (int n = 0; n < 5; ++n) {
        dS[n] = y_sh[wave][n][lane];
        dN[n] = y_sh[wave][n][64 + lane];
    }
    const float bsg = b_sage[lane];
    float agg0 = (md[0] * dN[1] + md[1] * dN[2] + md[2] * dN[3] + md[3] * dN[4]) / degs;
    float p = fmaxf(dS[0] + agg0 + bsg, 0.f);
    #pragma unroll
    for (int d = 0; d < 4; ++d)
        p += fmaxf(dS[d + 1] + md[d] * dN[0] + bsg, 0.f);

    pooled[(size_t)bt * 64 + lane] = p * 0.2f;
}

// ---------------------------------------------------------------------------
// Kernel 3: bidirectional GRU (lanes 0-31 fwd, 32-63 bwd) + output assembly.
// ---------------------------------------------------------------------------
__global__ __launch_bounds__(256) void gru_kernel(
    const float* __restrict__ pooled, const unsigned short* __restrict__ emb,
    const float* __restrict__ Wx_f, const float* __restrict__ Wh_f,
    const float* __restrict__ bx_f, const float* __restrict__ bh_f,
    const float* __restrict__ Wx_b, const float* __restrict__ Wh_b,
    const float* __restrict__ bx_b, const float* __restrict__ bh_b,
    float* __restrict__ out)
{
    __shared__ float x_sh[4][5][64];
    __shared__ float h_sh[4][2][32];
    const int tid = threadIdx.x, wave = tid >> 6, lane = tid & 63;
    const int b = blockIdx.x * 4 + wave;

    #pragma unroll
    for (int t = 0; t < 5; ++t) x_sh[wave][t][lane] = pooled[(size_t)(b * 5 + t) * 64 + lane];

    const int j = lane & 31, dir = lane >> 5;
    const float* Wx = dir ? Wx_b : Wx_f;
    const float* Wh = dir ? Wh_b : Wh_f;
    const float* bx = dir ? bx_b : bx_f;
    const float* bh = dir ? bh_b : bh_f;
    const float bxr = bx[j], bxz = bx[32 + j], bxn = bx[64 + j];
    const float bhr = bh[j], bhz = bh[32 + j], bhn = bh[64 + j];
    float h = 0.f;
    __syncthreads();

    for (int s = 0; s < 5; ++s) {
        const int t = dir ? (4 - s) : s;
        h_sh[wave][dir][j] = h;
        __syncthreads();
        float xr = bxr, xz = bxz, xn = bxn;
        for (int f = 0; f < 64; ++f) {
            float xv = x_sh[wave][t][f];
            xr = fmaf(xv, Wx[f * 96 + j], xr);
            xz = fmaf(xv, Wx[f * 96 + 32 + j], xz);
            xn = fmaf(xv, Wx[f * 96 + 64 + j], xn);
        }
        float hr = bhr, hz = bhz, hn = bhn;
        for (int f = 0; f < 32; ++f) {
            float hv = h_sh[wave][dir][f];
            hr = fmaf(hv, Wh[f * 96 + j], hr);
            hz = fmaf(hv, Wh[f * 96 + 32 + j], hz);
            hn = fmaf(hv, Wh[f * 96 + 64 + j], hn);
        }
        float rr = 1.f / (1.f + __expf(-(xr + hr)));
        float zz = 1.f / (1.f + __expf(-(xz + hz)));
        float ni = xn + rr * hn;
        ni = fminf(fmaxf(ni, -15.f), 15.f);
        float e2 = __expf(2.f * ni);
        float nn = (e2 - 1.f) / (e2 + 1.f);
        h = (1.f - zz) * nn + zz * h;
        __syncthreads();
    }

    out[(size_t)b * 320 + 256 + dir * 32 + j] = h;
    const unsigned short* se = emb + (size_t)((b * 5 + 4) * 5) * 256;
    #pragma unroll
    for (int c = 0; c < 4; ++c)
        out[(size_t)b * 320 + c * 64 + lane] = bf2f(se[c * 64 + lane]);
}

// ---------------------------------------------------------------------------
extern "C" void kernel_launch(void* const* d_in, const int* in_sizes, int n_in,
                              void* d_out, int out_size, void* d_ws, size_t ws_size,
                              hipStream_t stream) {
    (void)in_sizes; (void)n_in; (void)out_size; (void)ws_size;
    const float* self_feat = (const float*)d_in[0];
    const float* nbr_feat  = (const float*)d_in[1];
    const float* W_in   = (const float*)d_in[2];
    const float* b_in_  = (const float*)d_in[3];
    const float* ln_g   = (const float*)d_in[4];
    const float* ln_b   = (const float*)d_in[5];
    const float* W_coop = (const float*)d_in[6];
    const float* as_c   = (const float*)d_in[7];
    const float* ad_c   = (const float*)d_in[8];
    const float* W_conf = (const float*)d_in[9];
    const float* as_f   = (const float*)d_in[10];
    const float* ad_f   = (const float*)d_in[11];
    const float* W_self = (const float*)d_in[12];
    const float* W_neigh= (const float*)d_in[13];
    const float* b_sage = (const float*)d_in[14];
    const float* Wx_f   = (const float*)d_in[15];
    const float* Wh_f   = (const float*)d_in[16];
    const float* bx_f   = (const float*)d_in[17];
    const float* bh_f   = (const float*)d_in[18];
    const float* Wx_b   = (const float*)d_in[19];
    const float* Wh_b   = (const float*)d_in[20];
    const float* bx_b   = (const float*)d_in[21];
    const float* bh_b   = (const float*)d_in[22];
    const float* adj_coop = (const float*)d_in[23];
    const float* adj_conf = (const float*)d_in[24];
    const int*   mask   = (const int*)d_in[25];
    float* out = (float*)d_out;

    unsigned short* bfrag = (unsigned short*)((char*)d_ws + OFF_BFRAG);
    int*            adjm  = (int*)((char*)d_ws + OFF_ADJ);
    unsigned short* sfrag = (unsigned short*)((char*)d_ws + OFF_SFRAG);
    unsigned short* emb   = (unsigned short*)((char*)d_ws + OFF_EMB);
    float*          pooled= (float*)((char*)d_ws + OFF_POOLED);

    prep_kernel<<<32, 256, 0, stream>>>(W_coop, as_c, ad_c, W_conf, as_f, ad_f,
                                        W_self, W_neigh, adj_coop, adj_conf,
                                        bfrag, adjm, sfrag);
    gat_kernel<<<GTOT / 4, 256, 0, stream>>>(self_feat, nbr_feat, W_in, b_in_, ln_g, ln_b,
                                             bfrag, adjm, emb);
    sage_kernel<<<(BB * TT) / 4, 256, 0, stream>>>(emb, mask, sfrag, b_sage, pooled);
    gru_kernel<<<BB / 4, 256, 0, stream>>>(pooled, emb,
        Wx_f, Wh_f, bx_f, bh_f, Wx_b, Wh_b, bx_b, bh_b, out);
}

// Round 5
// 400.136 us; speedup vs baseline: 5.7933x; 1.0848x over previous
//
#include <hip/hip_runtime.h>
#include <hip/hip_bf16.h>

#define BB 4096
#define TT 5
#define GTOT (BB * TT * 5)        // 102400 graphs; emb row = b*25 + t*5 + node

// workspace byte offsets (total ~57.8 MB; bf16 emb everywhere)
#define OFF_BFRAG  0              // 17408 bf16 = 34816 B (gat B-fragments)
#define OFF_ADJ    36864          // 32 ints (adj masks [2][16])
#define OFF_SFRAG  40960          // 32768 bf16 = 65536 B (sage B-fragments)
#define OFF_EMB    106496         // 102400*256 bf16 = 52428800 B
#define OFF_POOLED 52535296ULL    // 20480*64 f32 = 5242880 B

typedef __bf16 bf16x8_t __attribute__((ext_vector_type(8)));
typedef short  s16x4_t  __attribute__((ext_vector_type(4)));
typedef float  f32x4_t  __attribute__((ext_vector_type(4)));

static __device__ __forceinline__ unsigned short f2bf(float v) {
    return __builtin_bit_cast(unsigned short, __float2bfloat16(v));
}
static __device__ __forceinline__ float bf2f(unsigned short u) {
    return __builtin_bit_cast(float, ((unsigned int)u) << 16);
}

// ---------------------------------------------------------------------------
// Prep: B-fragments for gat GEMM (17 tiles x 2 ksteps), sage GEMM
// (8 tiles x 8 ksteps), and adjacency bitmasks.
// gat  B[k][n]: n<256 -> W[pair p=n>>5][k][o=n&31]; n in [256,264): u_src[p][k];
//               n in [264,272): u_dst[p][k].  idx = ((it*2+ks)*64+l)*8+j,
//               k = ks*32+(l>>4)*8+j, n = it*16+(l&15).
// sage B[k][n]: n<64 -> W_self[k][n]; else W_neigh[k][n-64]. idx=((nt*8+ks)*64+l)*8+j.
// ---------------------------------------------------------------------------
__global__ void prep_kernel(
    const float* __restrict__ W_coop, const float* __restrict__ as_c, const float* __restrict__ ad_c,
    const float* __restrict__ W_conf, const float* __restrict__ as_f, const float* __restrict__ ad_f,
    const float* __restrict__ W_self, const float* __restrict__ W_neigh,
    const float* __restrict__ adj_coop, const float* __restrict__ adj_conf,
    unsigned short* __restrict__ bfrag, int* __restrict__ adjm_g,
    unsigned short* __restrict__ sfrag)
{
    const int gtid = blockIdx.x * 256 + threadIdx.x;
    const int gstride = gridDim.x * 256;

    for (int idx = gtid; idx < 17408; idx += gstride) {
        int j = idx & 7, l = (idx >> 3) & 63;
        int rest = idx >> 9, ks = rest & 1, it = rest >> 1;
        int k = ks * 32 + ((l >> 4) << 3) + j;
        int n = it * 16 + (l & 15);
        float val;
        if (n < 256) {
            int p = n >> 5, o = n & 31, head = p & 3;
            const float* W = (p >> 2) ? W_conf : W_coop;
            val = W[(head * 64 + k) * 32 + o];
        } else {
            int c = n - 256, sd = c >> 3, p = c & 7;
            int gat = p >> 2, head = p & 3;
            const float* W = gat ? W_conf : W_coop;
            const float* a = sd ? (gat ? ad_f : ad_c) : (gat ? as_f : as_c);
            float s = 0.f;
            for (int o = 0; o < 32; ++o) s = fmaf(W[(head * 64 + k) * 32 + o], a[head * 32 + o], s);
            val = s;
        }
        bfrag[idx] = f2bf(val);
    }

    for (int idx = gtid; idx < 32768; idx += gstride) {
        int j = idx & 7, l = (idx >> 3) & 63;
        int rest = idx >> 9, ks = rest & 7, nt = rest >> 3;
        int k = ks * 32 + ((l >> 4) << 3) + j;
        int n = nt * 16 + (l & 15);
        float v = (n < 64) ? W_self[k * 64 + n] : W_neigh[k * 64 + (n - 64)];
        sfrag[idx] = f2bf(v);
    }

    if (gtid < 32) {
        int gat = gtid >> 4, n = gtid & 15;
        int m = 0;
        if (n < 12) {
            const float* adj = gat ? adj_conf : adj_coop;
            for (int c = 0; c < 12; ++c) if (adj[n * 12 + c] > 0.f) m |= (1 << c);
        }
        adjm_g[gtid] = m;
    }
}

// ---------------------------------------------------------------------------
// Kernel 1: GAT encoder. One wave per graph, 4 independent waves/block,
// no barriers. h computed DIRECTLY in A-fragment layout (lane m=lane&15 owns
// row m's k-slice); LN reduction = 2 shfl_xor over the 4 lanes sharing m.
// ---------------------------------------------------------------------------
__global__ __launch_bounds__(256) void gat_kernel(
    const float* __restrict__ self_feat, const float* __restrict__ nbr_feat,
    const float* __restrict__ W_in, const float* __restrict__ b_in,
    const float* __restrict__ ln_g, const float* __restrict__ ln_b,
    const unsigned short* __restrict__ bfrag, const int* __restrict__ adjm_g,
    unsigned short* __restrict__ emb)
{
    __shared__ float          sc_sh[4][16][12];       // 3072 B  [col(0-7 src,8-15 dst)][node]
    __shared__ unsigned short attn_sh[4][8][16][20];  // 20480 B, rows padded to 40 B

    const int tid = threadIdx.x, wave = tid >> 6, lane = tid & 63;
    const int lg = lane >> 4, m = lane & 15;

    // ---- graph decode ----
    const int g = blockIdx.x * 4 + wave;
    const int b = g / 25, r_ = g % 25, t = r_ / 5, node = r_ % 5;
    const float* x = (node == 0) ? (self_feat + (size_t)(b * 5 + t) * 48)
                                 : (nbr_feat + (size_t)((b * 4 + (node - 1)) * 5 + t) * 48);

    // ---- h[m][k] in fragment layout: k = ks*32 + lg*8 + j ----
    float hr[2][8];
    {
        float4 xv = make_float4(0.f, 0.f, 0.f, 0.f);
        if (m < 12) xv = *(const float4*)(x + m * 4);
        const float xc[4] = {xv.x, xv.y, xv.z, xv.w};
        #pragma unroll
        for (int ks = 0; ks < 2; ++ks) {
            const int k0 = ks * 32 + lg * 8;
            float4 bv0 = *(const float4*)(b_in + k0);
            float4 bv1 = *(const float4*)(b_in + k0 + 4);
            hr[ks][0] = bv0.x; hr[ks][1] = bv0.y; hr[ks][2] = bv0.z; hr[ks][3] = bv0.w;
            hr[ks][4] = bv1.x; hr[ks][5] = bv1.y; hr[ks][6] = bv1.z; hr[ks][7] = bv1.w;
            #pragma unroll
            for (int c = 0; c < 4; ++c) {
                float4 w0 = *(const float4*)(W_in + c * 64 + k0);
                float4 w1 = *(const float4*)(W_in + c * 64 + k0 + 4);
                hr[ks][0] = fmaf(xc[c], w0.x, hr[ks][0]);
                hr[ks][1] = fmaf(xc[c], w0.y, hr[ks][1]);
                hr[ks][2] = fmaf(xc[c], w0.z, hr[ks][2]);
                hr[ks][3] = fmaf(xc[c], w0.w, hr[ks][3]);
                hr[ks][4] = fmaf(xc[c], w1.x, hr[ks][4]);
                hr[ks][5] = fmaf(xc[c], w1.y, hr[ks][5]);
                hr[ks][6] = fmaf(xc[c], w1.z, hr[ks][6]);
                hr[ks][7] = fmaf(xc[c], w1.w, hr[ks][7]);
            }
        }
    }

    // ---- LayerNorm: row-sum over 64 feats = lane partial + 2-step butterfly ----
    float s = 0.f, q = 0.f;
    #pragma unroll
    for (int ks = 0; ks < 2; ++ks)
        #pragma unroll
        for (int j = 0; j < 8; ++j) { s += hr[ks][j]; q = fmaf(hr[ks][j], hr[ks][j], q); }
    s += __shfl_xor(s, 16, 64); s += __shfl_xor(s, 32, 64);
    q += __shfl_xor(q, 16, 64); q += __shfl_xor(q, 32, 64);
    const float mu = s * (1.f / 64.f);
    const float rstd = rsqrtf(fmaxf(q * (1.f / 64.f) - mu * mu, 0.f) + 1e-5f);
    const float keep = (m < 12) ? 1.f : 0.f;

    bf16x8_t afrag[2];
    #pragma unroll
    for (int ks = 0; ks < 2; ++ks) {
        const int k0 = ks * 32 + lg * 8;
        float4 g0 = *(const float4*)(ln_g + k0);
        float4 g1 = *(const float4*)(ln_g + k0 + 4);
        float4 lb0 = *(const float4*)(ln_b + k0);
        float4 lb1 = *(const float4*)(ln_b + k0 + 4);
        const float gg[8] = {g0.x, g0.y, g0.z, g0.w, g1.x, g1.y, g1.z, g1.w};
        const float bb[8] = {lb0.x, lb0.y, lb0.z, lb0.w, lb1.x, lb1.y, lb1.z, lb1.w};
        #pragma unroll
        for (int j = 0; j < 8; ++j) {
            float v = fmaf((hr[ks][j] - mu) * rstd, gg[j], bb[j]);
            v = fmaxf(v, 0.f) * keep;                 // ReLU; zero junk rows 12-15
            afrag[ks][j] = (__bf16)v;
        }
    }

    // ---- main GEMM: C[16 x 272] = h[16x64] @ B[64x272]; B streamed from L1 ----
    f32x4_t acc[17];
    #pragma unroll
    for (int it = 0; it < 17; ++it) acc[it] = (f32x4_t){0.f, 0.f, 0.f, 0.f};
    #pragma unroll
    for (int it = 0; it < 17; ++it) {
        #pragma unroll
        for (int ks = 0; ks < 2; ++ks) {
            bf16x8_t bfr = *(const bf16x8_t*)&bfrag[(size_t)((it * 2 + ks) * 64 + lane) * 8];
            acc[it] = __builtin_amdgcn_mfma_f32_16x16x32_bf16(afrag[ks], bfr, acc[it], 0, 0, 0);
        }
    }

    // ---- tile 16 = attention scores: sc[col=m][node row] ----
    if (lg < 3) {
        #pragma unroll
        for (int r = 0; r < 4; ++r) sc_sh[wave][m][lg * 4 + r] = acc[16][r];
    }
    __asm__ volatile("" ::: "memory");

    // ---- softmax once per (pair,row): 128 tasks / 2 passes; no max-sub ----
    #pragma unroll
    for (int jj = 0; jj < 2; ++jj) {
        int v = jj * 64 + lane;
        int p = v >> 4, n = v & 15;
        uint2* arow = (uint2*)&attn_sh[wave][p][n][0];
        if (n < 12) {
            float ssrc = sc_sh[wave][p][n];
            float4 d0 = *(const float4*)&sc_sh[wave][8 + p][0];
            float4 d1 = *(const float4*)&sc_sh[wave][8 + p][4];
            float4 d2 = *(const float4*)&sc_sh[wave][8 + p][8];
            float dm[12] = {d0.x, d0.y, d0.z, d0.w, d1.x, d1.y, d1.z, d1.w, d2.x, d2.y, d2.z, d2.w};
            int am = adjm_g[(p >> 2) * 16 + n];
            float pr[12]; float ssum = 0.f;
            #pragma unroll
            for (int mm = 0; mm < 12; ++mm) {
                float tv = ssrc + dm[mm];
                tv = fmaxf(tv, 0.2f * tv);                 // leaky_relu(0.2)
                float pp = ((am >> mm) & 1) ? __expf(tv) : 0.f;
                ssum += pp; pr[mm] = pp;
            }
            float inv = 1.f / ssum;
            unsigned int u[12];
            #pragma unroll
            for (int mm = 0; mm < 12; ++mm) u[mm] = (unsigned int)f2bf(pr[mm] * inv);
            arow[0] = make_uint2(u[0] | (u[1] << 16), u[2]  | (u[3]  << 16));
            arow[1] = make_uint2(u[4] | (u[5] << 16), u[6]  | (u[7]  << 16));
            arow[2] = make_uint2(u[8] | (u[9] << 16), u[10] | (u[11] << 16));
            arow[3] = make_uint2(0u, 0u);                  // cols 12-15 (read by PV)
        } else {
            arow[0] = make_uint2(0u, 0u); arow[1] = make_uint2(0u, 0u);
            arow[2] = make_uint2(0u, 0u); arow[3] = make_uint2(0u, 0u);
        }
    }
    __asm__ volatile("" ::: "memory");

    // ---- PV via 16x16x16 MFMA: B-frag IS the main-GEMM C-register block ----
    const f32x4_t zero4 = (f32x4_t){0.f, 0.f, 0.f, 0.f};
    #pragma unroll
    for (int p = 0; p < 8; ++p) {
        s16x4_t afr = *(const s16x4_t*)&attn_sh[wave][p][m][lg << 2];
        #pragma unroll
        for (int tt = 0; tt < 2; ++tt) {
            const int it = p * 2 + tt;
            s16x4_t bfr;
            bfr[0] = (short)f2bf(acc[it][0]);
            bfr[1] = (short)f2bf(acc[it][1]);
            bfr[2] = (short)f2bf(acc[it][2]);
            bfr[3] = (short)f2bf(acc[it][3]);
            f32x4_t pv = __builtin_amdgcn_mfma_f32_16x16x16bf16_1k(afr, bfr, zero4, 0, 0, 0);
            float ss = 0.f;
            #pragma unroll
            for (int r = 0; r < 4; ++r) {
                float xv = pv[r];
                xv = (xv > 0.f) ? xv : (__expf(xv) - 1.f);  // ELU (pad rows contribute 0)
                ss += xv;
            }
            ss += __shfl_xor(ss, 16, 64);
            ss += __shfl_xor(ss, 32, 64);
            if (lane < 16)
                emb[(size_t)g * 256 + p * 32 + tt * 16 + lane] = f2bf(ss * (1.f / 12.f));
        }
    }
}

// ---------------------------------------------------------------------------
// Kernel 2: GraphSAGE via MFMA. One wave per (b,t): Y[16x128] = X[16x256]@Wsn,
// A-frags loaded directly from emb in fragment layout; combine in-wave.
// ---------------------------------------------------------------------------
__global__ __launch_bounds__(256) void sage_kernel(
    const unsigned short* __restrict__ emb, const int* __restrict__ mask,
    const unsigned short* __restrict__ sfrag, const float* __restrict__ b_sage,
    float* __restrict__ pooled)
{
    __shared__ float y_sh[4][5][128];                 // 10240 B
    const int tid = threadIdx.x, wave = tid >> 6, lane = tid & 63;
    const int bt = blockIdx.x * 4 + wave;             // 0..20479
    const int b = bt / 5;
    const int lg = lane >> 4, row = lane & 15;

    bf16x8_t afr[8];
    if (row < 5) {
        const unsigned short* base = emb + (size_t)(bt * 5 + row) * 256 + lg * 8;
        #pragma unroll
        for (int ks = 0; ks < 8; ++ks) afr[ks] = *(const bf16x8_t*)(base + ks * 32);
    } else {
        #pragma unroll
        for (int ks = 0; ks < 8; ++ks) {
            uint4 z = make_uint4(0u, 0u, 0u, 0u);
            afr[ks] = __builtin_bit_cast(bf16x8_t, z);
        }
    }

    #pragma unroll
    for (int nt = 0; nt < 8; ++nt) {
        f32x4_t acc = (f32x4_t){0.f, 0.f, 0.f, 0.f};
        #pragma unroll
        for (int ks = 0; ks < 8; ++ks) {
            bf16x8_t bfr = *(const bf16x8_t*)&sfrag[(size_t)((nt * 8 + ks) * 64 + lane) * 8];
            acc = __builtin_amdgcn_mfma_f32_16x16x32_bf16(afr[ks], bfr, acc, 0, 0, 0);
        }
        #pragma unroll
        for (int r = 0; r < 4; ++r) {
            int rw = lg * 4 + r;
            if (rw < 5) y_sh[wave][rw][nt * 16 + row] = acc[r];
        }
    }
    __asm__ volatile("" ::: "memory");

    float md[4];
    #pragma unroll
    for (int d = 0; d < 4; ++d) md[d] = (float)mask[b * 4 + d];
    const float degs = fmaxf(md[0] + md[1] + md[2] + md[3], 1.f);

    float dS[5], dN[5];
    #pragma unroll
    for (int n = 0; n < 5; ++n) {
        dS[n] = y_sh[wave][n][lane];
        dN[n] = y_sh[wave][n][64 + lane];
    }
    const float bsg = b_sage[lane];
    float agg0 = (md[0] * dN[1] + md[1] * dN[2] + md[2] * dN[3] + md[3] * dN[4]) / degs;
    float p = fmaxf(dS[0] + agg0 + bsg, 0.f);
    #pragma unroll
    for (int d = 0; d < 4; ++d)
        p += fmaxf(dS[d + 1] + md[d] * dN[0] + bsg, 0.f);

    pooled[(size_t)bt * 64 + lane] = p * 0.2f;
}

// ---------------------------------------------------------------------------
// Kernel 3: bidirectional GRU (lanes 0-31 fwd, 32-63 bwd) + output assembly.
// ---------------------------------------------------------------------------
__global__ __launch_bounds__(256) void gru_kernel(
    const float* __restrict__ pooled, const unsigned short* __restrict__ emb,
    const float* __restrict__ Wx_f, const float* __restrict__ Wh_f,
    const float* __restrict__ bx_f, const float* __restrict__ bh_f,
    const float* __restrict__ Wx_b, const float* __restrict__ Wh_b,
    const float* __restrict__ bx_b, const float* __restrict__ bh_b,
    float* __restrict__ out)
{
    __shared__ float x_sh[4][5][64];
    __shared__ float h_sh[4][2][32];
    const int tid = threadIdx.x, wave = tid >> 6, lane = tid & 63;
    const int b = blockIdx.x * 4 + wave;

    #pragma unroll
    for (int t = 0; t < 5; ++t) x_sh[wave][t][lane] = pooled[(size_t)(b * 5 + t) * 64 + lane];

    const int j = lane & 31, dir = lane >> 5;
    const float* Wx = dir ? Wx_b : Wx_f;
    const float* Wh = dir ? Wh_b : Wh_f;
    const float* bx = dir ? bx_b : bx_f;
    const float* bh = dir ? bh_b : bh_f;
    const float bxr = bx[j], bxz = bx[32 + j], bxn = bx[64 + j];
    const float bhr = bh[j], bhz = bh[32 + j], bhn = bh[64 + j];
    float h = 0.f;
    __syncthreads();

    for (int s = 0; s < 5; ++s) {
        const int t = dir ? (4 - s) : s;
        h_sh[wave][dir][j] = h;
        __syncthreads();
        float xr = bxr, xz = bxz, xn = bxn;
        for (int f = 0; f < 64; ++f) {
            float xv = x_sh[wave][t][f];
            xr = fmaf(xv, Wx[f * 96 + j], xr);
            xz = fmaf(xv, Wx[f * 96 + 32 + j], xz);
            xn = fmaf(xv, Wx[f * 96 + 64 + j], xn);
        }
        float hr = bhr, hz = bhz, hn = bhn;
        for (int f = 0; f < 32; ++f) {
            float hv = h_sh[wave][dir][f];
            hr = fmaf(hv, Wh[f * 96 + j], hr);
            hz = fmaf(hv, Wh[f * 96 + 32 + j], hz);
            hn = fmaf(hv, Wh[f * 96 + 64 + j], hn);
        }
        float rr = 1.f / (1.f + __expf(-(xr + hr)));
        float zz = 1.f / (1.f + __expf(-(xz + hz)));
        float ni = xn + rr * hn;
        ni = fminf(fmaxf(ni, -15.f), 15.f);
        float e2 = __expf(2.f * ni);
        float nn = (e2 - 1.f) / (e2 + 1.f);
        h = (1.f - zz) * nn + zz * h;
        __syncthreads();
    }

    out[(size_t)b * 320 + 256 + dir * 32 + j] = h;
    const unsigned short* se = emb + (size_t)((b * 5 + 4) * 5) * 256;
    #pragma unroll
    for (int c = 0; c < 4; ++c)
        out[(size_t)b * 320 + c * 64 + lane] = bf2f(se[c * 64 + lane]);
}

// ---------------------------------------------------------------------------
extern "C" void kernel_launch(void* const* d_in, const int* in_sizes, int n_in,
                              void* d_out, int out_size, void* d_ws, size_t ws_size,
                              hipStream_t stream) {
    (void)in_sizes; (void)n_in; (void)out_size; (void)ws_size;
    const float* self_feat = (const float*)d_in[0];
    const float* nbr_feat  = (const float*)d_in[1];
    const float* W_in   = (const float*)d_in[2];
    const float* b_in_  = (const float*)d_in[3];
    const float* ln_g   = (const float*)d_in[4];
    const float* ln_b   = (const float*)d_in[5];
    const float* W_coop = (const float*)d_in[6];
    const float* as_c   = (const float*)d_in[7];
    const float* ad_c   = (const float*)d_in[8];
    const float* W_conf = (const float*)d_in[9];
    const float* as_f   = (const float*)d_in[10];
    const float* ad_f   = (const float*)d_in[11];
    const float* W_self = (const float*)d_in[12];
    const float* W_neigh= (const float*)d_in[13];
    const float* b_sage = (const float*)d_in[14];
    const float* Wx_f   = (const float*)d_in[15];
    const float* Wh_f   = (const float*)d_in[16];
    const float* bx_f   = (const float*)d_in[17];
    const float* bh_f   = (const float*)d_in[18];
    const float* Wx_b   = (const float*)d_in[19];
    const float* Wh_b   = (const float*)d_in[20];
    const float* bx_b   = (const float*)d_in[21];
    const float* bh_b   = (const float*)d_in[22];
    const float* adj_coop = (const float*)d_in[23];
    const float* adj_conf = (const float*)d_in[24];
    const int*   mask   = (const int*)d_in[25];
    float* out = (float*)d_out;

    unsigned short* bfrag = (unsigned short*)((char*)d_ws + OFF_BFRAG);
    int*            adjm  = (int*)((char*)d_ws + OFF_ADJ);
    unsigned short* sfrag = (unsigned short*)((char*)d_ws + OFF_SFRAG);
    unsigned short* emb   = (unsigned short*)((char*)d_ws + OFF_EMB);
    float*          pooled= (float*)((char*)d_ws + OFF_POOLED);

    prep_kernel<<<32, 256, 0, stream>>>(W_coop, as_c, ad_c, W_conf, as_f, ad_f,
                                        W_self, W_neigh, adj_coop, adj_conf,
                                        bfrag, adjm, sfrag);
    gat_kernel<<<GTOT / 4, 256, 0, stream>>>(self_feat, nbr_feat, W_in, b_in_, ln_g, ln_b,
                                             bfrag, adjm, emb);
    sage_kernel<<<(BB * TT) / 4, 256, 0, stream>>>(emb, mask, sfrag, b_sage, pooled);
    gru_kernel<<<BB / 4, 256, 0, stream>>>(pooled, emb,
        Wx_f, Wh_f, bx_f, bh_f, Wx_b, Wh_b, bx_b, bh_b, out);
}

// Round 6
// 331.505 us; speedup vs baseline: 6.9926x; 1.2070x over previous
//
#include <hip/hip_runtime.h>
#include <hip/hip_bf16.h>

#define BB 4096
#define TT 5
#define GTOT (BB * TT * 5)        // 102400 graphs; emb row = b*25 + t*5 + node

// workspace byte offsets (total ~57.8 MB; bf16 emb everywhere)
#define OFF_BFRAG  0              // 17408 bf16 = 34816 B (gat B-fragments)
#define OFF_ADJ    36864          // 32 ints (adj masks [2][16])
#define OFF_SFRAG  40960          // 32768 bf16 = 65536 B (sage B-fragments)
#define OFF_EMB    106496         // 102400*256 bf16 = 52428800 B
#define OFF_POOLED 52535296ULL    // 20480*64 f32 = 5242880 B

typedef __bf16 bf16x8_t __attribute__((ext_vector_type(8)));
typedef __bf16 bf16x4_t __attribute__((ext_vector_type(4)));
typedef __bf16 bf16x2_t __attribute__((ext_vector_type(2)));
typedef short  s16x4_t  __attribute__((ext_vector_type(4)));
typedef float  f32x4_t  __attribute__((ext_vector_type(4)));

static __device__ __forceinline__ unsigned short f2bf(float v) {
    return __builtin_bit_cast(unsigned short, (__bf16)v);
}

// ---------------------------------------------------------------------------
// Prep: B-fragments for gat GEMM (17 tiles x 2 ksteps), sage GEMM
// (8 tiles x 8 ksteps), and adjacency bitmasks.
// gat  B[k][n]: n<256 -> W[pair p=n>>5][k][o=n&31]; n in [256,264): u_src[p][k];
//               n in [264,272): u_dst[p][k].  idx = ((it*2+ks)*64+l)*8+j,
//               k = ks*32+(l>>4)*8+j, n = it*16+(l&15).
// sage B[k][n]: n<64 -> W_self[k][n]; else W_neigh[k][n-64]. idx=((nt*8+ks)*64+l)*8+j.
// ---------------------------------------------------------------------------
__global__ void prep_kernel(
    const float* __restrict__ W_coop, const float* __restrict__ as_c, const float* __restrict__ ad_c,
    const float* __restrict__ W_conf, const float* __restrict__ as_f, const float* __restrict__ ad_f,
    const float* __restrict__ W_self, const float* __restrict__ W_neigh,
    const float* __restrict__ adj_coop, const float* __restrict__ adj_conf,
    unsigned short* __restrict__ bfrag, int* __restrict__ adjm_g,
    unsigned short* __restrict__ sfrag)
{
    const int gtid = blockIdx.x * 256 + threadIdx.x;
    const int gstride = gridDim.x * 256;

    for (int idx = gtid; idx < 17408; idx += gstride) {
        int j = idx & 7, l = (idx >> 3) & 63;
        int rest = idx >> 9, ks = rest & 1, it = rest >> 1;
        int k = ks * 32 + ((l >> 4) << 3) + j;
        int n = it * 16 + (l & 15);
        float val;
        if (n < 256) {
            int p = n >> 5, o = n & 31, head = p & 3;
            const float* W = (p >> 2) ? W_conf : W_coop;
            val = W[(head * 64 + k) * 32 + o];
        } else {
            int c = n - 256, sd = c >> 3, p = c & 7;
            int gat = p >> 2, head = p & 3;
            const float* W = gat ? W_conf : W_coop;
            const float* a = sd ? (gat ? ad_f : ad_c) : (gat ? as_f : as_c);
            float s = 0.f;
            for (int o = 0; o < 32; ++o) s = fmaf(W[(head * 64 + k) * 32 + o], a[head * 32 + o], s);
            val = s;
        }
        bfrag[idx] = f2bf(val);
    }

    for (int idx = gtid; idx < 32768; idx += gstride) {
        int j = idx & 7, l = (idx >> 3) & 63;
        int rest = idx >> 9, ks = rest & 7, nt = rest >> 3;
        int k = ks * 32 + ((l >> 4) << 3) + j;
        int n = nt * 16 + (l & 15);
        float v = (n < 64) ? W_self[k * 64 + n] : W_neigh[k * 64 + (n - 64)];
        sfrag[idx] = f2bf(v);
    }

    if (gtid < 32) {
        int gat = gtid >> 4, n = gtid & 15;
        int m = 0;
        if (n < 12) {
            const float* adj = gat ? adj_conf : adj_coop;
            for (int c = 0; c < 12; ++c) if (adj[n * 12 + c] > 0.f) m |= (1 << c);
        }
        adjm_g[gtid] = m;
    }
}

// ---------------------------------------------------------------------------
// Kernel 1: GAT encoder. One wave per graph, 4 independent waves/block, no
// barriers. Streaming N-tile schedule: scores tile -> softmax -> fused
// {2 main MFMA -> cvt -> PV MFMA -> ELU -> store} per (p,tt). Live acc = 4
// regs instead of 68 AGPRs -> target 8 waves/SIMD.
// ---------------------------------------------------------------------------
__global__ __launch_bounds__(256) void gat_kernel(
    const float* __restrict__ self_feat, const float* __restrict__ nbr_feat,
    const float* __restrict__ W_in, const float* __restrict__ b_in,
    const float* __restrict__ ln_g, const float* __restrict__ ln_b,
    const unsigned short* __restrict__ bfrag, const int* __restrict__ adjm_g,
    unsigned short* __restrict__ emb)
{
    __shared__ float          sc_sh[4][16][12];       // 3072 B  [col(0-7 src,8-15 dst)][node]
    __shared__ unsigned short attn_sh[4][8][16][20];  // 20480 B, rows padded to 40 B

    const int tid = threadIdx.x, wave = tid >> 6, lane = tid & 63;
    const int lg = lane >> 4, m = lane & 15;

    // ---- graph decode ----
    const int g = blockIdx.x * 4 + wave;
    const int b = g / 25, r_ = g % 25, t = r_ / 5, node = r_ % 5;
    const float* x = (node == 0) ? (self_feat + (size_t)(b * 5 + t) * 48)
                                 : (nbr_feat + (size_t)((b * 4 + (node - 1)) * 5 + t) * 48);

    // ---- h[m][k] in A-fragment layout: k = ks*32 + lg*8 + j ----
    float hr[2][8];
    {
        float4 xv = make_float4(0.f, 0.f, 0.f, 0.f);
        if (m < 12) xv = *(const float4*)(x + m * 4);
        const float xc[4] = {xv.x, xv.y, xv.z, xv.w};
        #pragma unroll
        for (int ks = 0; ks < 2; ++ks) {
            const int k0 = ks * 32 + lg * 8;
            float4 bv0 = *(const float4*)(b_in + k0);
            float4 bv1 = *(const float4*)(b_in + k0 + 4);
            hr[ks][0] = bv0.x; hr[ks][1] = bv0.y; hr[ks][2] = bv0.z; hr[ks][3] = bv0.w;
            hr[ks][4] = bv1.x; hr[ks][5] = bv1.y; hr[ks][6] = bv1.z; hr[ks][7] = bv1.w;
            #pragma unroll
            for (int c = 0; c < 4; ++c) {
                float4 w0 = *(const float4*)(W_in + c * 64 + k0);
                float4 w1 = *(const float4*)(W_in + c * 64 + k0 + 4);
                hr[ks][0] = fmaf(xc[c], w0.x, hr[ks][0]);
                hr[ks][1] = fmaf(xc[c], w0.y, hr[ks][1]);
                hr[ks][2] = fmaf(xc[c], w0.z, hr[ks][2]);
                hr[ks][3] = fmaf(xc[c], w0.w, hr[ks][3]);
                hr[ks][4] = fmaf(xc[c], w1.x, hr[ks][4]);
                hr[ks][5] = fmaf(xc[c], w1.y, hr[ks][5]);
                hr[ks][6] = fmaf(xc[c], w1.z, hr[ks][6]);
                hr[ks][7] = fmaf(xc[c], w1.w, hr[ks][7]);
            }
        }
    }

    // ---- LayerNorm: 2-step butterfly over the 4 lanes sharing row m ----
    float s = 0.f, q = 0.f;
    #pragma unroll
    for (int ks = 0; ks < 2; ++ks)
        #pragma unroll
        for (int j = 0; j < 8; ++j) { s += hr[ks][j]; q = fmaf(hr[ks][j], hr[ks][j], q); }
    s += __shfl_xor(s, 16, 64); s += __shfl_xor(s, 32, 64);
    q += __shfl_xor(q, 16, 64); q += __shfl_xor(q, 32, 64);
    const float mu = s * (1.f / 64.f);
    const float rstd = rsqrtf(fmaxf(q * (1.f / 64.f) - mu * mu, 0.f) + 1e-5f);
    const float keep = (m < 12) ? 1.f : 0.f;

    bf16x8_t afrag[2];
    #pragma unroll
    for (int ks = 0; ks < 2; ++ks) {
        const int k0 = ks * 32 + lg * 8;
        float4 g0 = *(const float4*)(ln_g + k0);
        float4 g1 = *(const float4*)(ln_g + k0 + 4);
        float4 lb0 = *(const float4*)(ln_b + k0);
        float4 lb1 = *(const float4*)(ln_b + k0 + 4);
        const float gg[8] = {g0.x, g0.y, g0.z, g0.w, g1.x, g1.y, g1.z, g1.w};
        const float bb[8] = {lb0.x, lb0.y, lb0.z, lb0.w, lb1.x, lb1.y, lb1.z, lb1.w};
        #pragma unroll
        for (int j = 0; j < 8; ++j) {
            float v = fmaf((hr[ks][j] - mu) * rstd, gg[j], bb[j]);
            v = fmaxf(v, 0.f) * keep;                 // ReLU; zero junk rows 12-15
            afrag[ks][j] = (__bf16)v;
        }
    }

    // ---- scores tile (it=16) first: sc[col=m][node row] ----
    {
        f32x4_t acc16 = (f32x4_t){0.f, 0.f, 0.f, 0.f};
        #pragma unroll
        for (int ks = 0; ks < 2; ++ks) {
            bf16x8_t bfr = *(const bf16x8_t*)&bfrag[(size_t)((32 + ks) * 64 + lane) * 8];
            acc16 = __builtin_amdgcn_mfma_f32_16x16x32_bf16(afrag[ks], bfr, acc16, 0, 0, 0);
        }
        if (lg < 3) {
            #pragma unroll
            for (int r = 0; r < 4; ++r) sc_sh[wave][m][lg * 4 + r] = acc16[r];
        }
    }
    __asm__ volatile("" ::: "memory");

    // ---- softmax once per (pair,row): 128 tasks / 2 passes; no max-sub ----
    #pragma unroll
    for (int jj = 0; jj < 2; ++jj) {
        int v = jj * 64 + lane;
        int p = v >> 4, n = v & 15;
        uint2* arow = (uint2*)&attn_sh[wave][p][n][0];
        const uint2 z2 = make_uint2(0u, 0u);
        if (n < 12) {
            float ssrc = sc_sh[wave][p][n];
            float4 d0 = *(const float4*)&sc_sh[wave][8 + p][0];
            float4 d1 = *(const float4*)&sc_sh[wave][8 + p][4];
            float4 d2 = *(const float4*)&sc_sh[wave][8 + p][8];
            float dm[12] = {d0.x, d0.y, d0.z, d0.w, d1.x, d1.y, d1.z, d1.w, d2.x, d2.y, d2.z, d2.w};
            int am = adjm_g[(p >> 2) * 16 + n];
            float pr[12]; float ssum = 0.f;
            #pragma unroll
            for (int mm = 0; mm < 12; ++mm) {
                float tv = ssrc + dm[mm];
                tv = fmaxf(tv, 0.2f * tv);                 // leaky_relu(0.2)
                float pp = ((am >> mm) & 1) ? __expf(tv) : 0.f;
                ssum += pp; pr[mm] = pp;
            }
            float inv = 1.f / ssum;
            unsigned int w[6];
            #pragma unroll
            for (int qq = 0; qq < 6; ++qq) {
                bf16x2_t pk;
                pk[0] = (__bf16)(pr[2 * qq] * inv);
                pk[1] = (__bf16)(pr[2 * qq + 1] * inv);
                w[qq] = __builtin_bit_cast(unsigned int, pk);
            }
            arow[0] = make_uint2(w[0], w[1]);
            arow[1] = make_uint2(w[2], w[3]);
            arow[2] = make_uint2(w[4], w[5]);
            arow[3] = z2;                                  // cols 12-15 (read by PV)
        } else {
            arow[0] = z2; arow[1] = z2; arow[2] = z2; arow[3] = z2;
        }
    }
    __asm__ volatile("" ::: "memory");

    // ---- fused main-GEMM + PV, streaming one 16-col tile at a time ----
    const f32x4_t zero4 = (f32x4_t){0.f, 0.f, 0.f, 0.f};
    #pragma unroll
    for (int p = 0; p < 8; ++p) {
        s16x4_t afr = *(const s16x4_t*)&attn_sh[wave][p][m][lg << 2];
        #pragma unroll
        for (int tt = 0; tt < 2; ++tt) {
            const int it = p * 2 + tt;
            f32x4_t acc = (f32x4_t){0.f, 0.f, 0.f, 0.f};
            #pragma unroll
            for (int ks = 0; ks < 2; ++ks) {
                bf16x8_t bfr = *(const bf16x8_t*)&bfrag[(size_t)((it * 2 + ks) * 64 + lane) * 8];
                acc = __builtin_amdgcn_mfma_f32_16x16x32_bf16(afrag[ks], bfr, acc, 0, 0, 0);
            }
            bf16x4_t bv;
            bv[0] = (__bf16)acc[0]; bv[1] = (__bf16)acc[1];
            bv[2] = (__bf16)acc[2]; bv[3] = (__bf16)acc[3];
            s16x4_t bfr2 = __builtin_bit_cast(s16x4_t, bv);
            f32x4_t pv = __builtin_amdgcn_mfma_f32_16x16x16bf16_1k(afr, bfr2, zero4, 0, 0, 0);
            float ss = 0.f;
            #pragma unroll
            for (int r = 0; r < 4; ++r) {
                float xv = pv[r];
                xv = (xv > 0.f) ? xv : (__expf(xv) - 1.f);  // ELU (pad rows contribute 0)
                ss += xv;
            }
            ss += __shfl_xor(ss, 16, 64);
            ss += __shfl_xor(ss, 32, 64);
            if (lane < 16)
                emb[(size_t)g * 256 + p * 32 + tt * 16 + lane] = f2bf(ss * (1.f / 12.f));
        }
    }
}

// ---------------------------------------------------------------------------
// Kernel 2: GraphSAGE via MFMA. One wave per (b,t): Y[16x128] = X[16x256]@Wsn,
// A-frags loaded directly from emb in fragment layout; combine in-wave.
// ---------------------------------------------------------------------------
__global__ __launch_bounds__(256) void sage_kernel(
    const unsigned short* __restrict__ emb, const int* __restrict__ mask,
    const unsigned short* __restrict__ sfrag, const float* __restrict__ b_sage,
    float* __restrict__ pooled)
{
    __shared__ float y_sh[4][5][128];                 // 10240 B
    const int tid = threadIdx.x, wave = tid >> 6, lane = tid & 63;
    const int bt = blockIdx.x * 4 + wave;             // 0..20479
    const int b = bt / 5;
    const int lg = lane >> 4, row = lane & 15;

    bf16x8_t afr[8];
    if (row < 5) {
        const unsigned short* base = emb + (size_t)(bt * 5 + row) * 256 + lg * 8;
        #pragma unroll
        for (int ks = 0; ks < 8; ++ks) afr[ks] = *(const bf16x8_t*)(base + ks * 32);
    } else {
        #pragma unroll
        for (int ks = 0; ks < 8; ++ks) {
            uint4 z = make_uint4(0u, 0u, 0u, 0u);
            afr[ks] = __builtin_bit_cast(bf16x8_t, z);
        }
    }

    #pragma unroll
    for (int nt = 0; nt < 8; ++nt) {
        f32x4_t acc = (f32x4_t){0.f, 0.f, 0.f, 0.f};
        #pragma unroll
        for (int ks = 0; ks < 8; ++ks) {
            bf16x8_t bfr = *(const bf16x8_t*)&sfrag[(size_t)((nt * 8 + ks) * 64 + lane) * 8];
            acc = __builtin_amdgcn_mfma_f32_16x16x32_bf16(afr[ks], bfr, acc, 0, 0, 0);
        }
        #pragma unroll
        for (int r = 0; r < 4; ++r) {
            int rw = lg * 4 + r;
            if (rw < 5) y_sh[wave][rw][nt * 16 + row] = acc[r];
        }
    }
    __asm__ volatile("" ::: "memory");

    float md[4];
    #pragma unroll
    for (int d = 0; d < 4; ++d) md[d] = (float)mask[b * 4 + d];
    const float degs = fmaxf(md[0] + md[1] + md[2] + md[3], 1.f);

    float dS[5], dN[5];
    #pragma unroll
    for (int n = 0; n < 5; ++n) {
        dS[n] = y_sh[wave][n][lane];
        dN[n] = y_sh[wave][n][64 + lane];
    }
    const float bsg = b_sage[lane];
    float agg0 = (md[0] * dN[1] + md[1] * dN[2] + md[2] * dN[3] + md[3] * dN[4]) / degs;
    float p = fmaxf(dS[0] + agg0 + bsg, 0.f);
    #pragma unroll
    for (int d = 0; d < 4; ++d)
        p += fmaxf(dS[d + 1] + md[d] * dN[0] + bsg, 0.f);

    pooled[(size_t)bt * 64 + lane] = p * 0.2f;
}

// ---------------------------------------------------------------------------
// Kernel 3: bidirectional GRU (lanes 0-31 fwd, 32-63 bwd) + output assembly.
// ---------------------------------------------------------------------------
__global__ __launch_bounds__(256) void gru_kernel(
    const float* __restrict__ pooled, const unsigned short* __restrict__ emb,
    const float* __restrict__ Wx_f, const float* __restrict__ Wh_f,
    const float* __restrict__ bx_f, const float* __restrict__ bh_f,
    const float* __restrict__ Wx_b, const float* __restrict__ Wh_b,
    const float* __restrict__ bx_b, const float* __restrict__ bh_b,
    float* __restrict__ out)
{
    __shared__ float x_sh[4][5][64];
    __shared__ float h_sh[4][2][32];
    const int tid = threadIdx.x, wave = tid >> 6, lane = tid & 63;
    const int b = blockIdx.x * 4 + wave;

    #pragma unroll
    for (int t = 0; t < 5; ++t) x_sh[wave][t][lane] = pooled[(size_t)(b * 5 + t) * 64 + lane];

    const int j = lane & 31, dir = lane >> 5;
    const float* Wx = dir ? Wx_b : Wx_f;
    const float* Wh = dir ? Wh_b : Wh_f;
    const float* bx = dir ? bx_b : bx_f;
    const float* bh = dir ? bh_b : bh_f;
    const float bxr = bx[j], bxz = bx[32 + j], bxn = bx[64 + j];
    const float bhr = bh[j], bhz = bh[32 + j], bhn = bh[64 + j];
    float h = 0.f;
    __syncthreads();

    for (int s = 0; s < 5; ++s) {
        const int t = dir ? (4 - s) : s;
        h_sh[wave][dir][j] = h;
        __syncthreads();
        float xr = bxr, xz = bxz, xn = bxn;
        for (int f = 0; f < 64; ++f) {
            float xv = x_sh[wave][t][f];
            xr = fmaf(xv, Wx[f * 96 + j], xr);
            xz = fmaf(xv, Wx[f * 96 + 32 + j], xz);
            xn = fmaf(xv, Wx[f * 96 + 64 + j], xn);
        }
        float hr = bhr, hz = bhz, hn = bhn;
        for (int f = 0; f < 32; ++f) {
            float hv = h_sh[wave][dir][f];
            hr = fmaf(hv, Wh[f * 96 + j], hr);
            hz = fmaf(hv, Wh[f * 96 + 32 + j], hz);
            hn = fmaf(hv, Wh[f * 96 + 64 + j], hn);
        }
        float rr = 1.f / (1.f + __expf(-(xr + hr)));
        float zz = 1.f / (1.f + __expf(-(xz + hz)));
        float ni = xn + rr * hn;
        ni = fminf(fmaxf(ni, -15.f), 15.f);
        float e2 = __expf(2.f * ni);
        float nn = (e2 - 1.f) / (e2 + 1.f);
        h = (1.f - zz) * nn + zz * h;
        __syncthreads();
    }

    out[(size_t)b * 320 + 256 + dir * 32 + j] = h;
    const unsigned short* se = emb + (size_t)((b * 5 + 4) * 5) * 256;
    #pragma unroll
    for (int c = 0; c < 4; ++c)
        out[(size_t)b * 320 + c * 64 + lane] = __builtin_bit_cast(float, ((unsigned int)se[c * 64 + lane]) << 16);
}

// ---------------------------------------------------------------------------
extern "C" void kernel_launch(void* const* d_in, const int* in_sizes, int n_in,
                              void* d_out, int out_size, void* d_ws, size_t ws_size,
                              hipStream_t stream) {
    (void)in_sizes; (void)n_in; (void)out_size; (void)ws_size;
    const float* self_feat = (const float*)d_in[0];
    const float* nbr_feat  = (const float*)d_in[1];
    const float* W_in   = (const float*)d_in[2];
    const float* b_in_  = (const float*)d_in[3];
    const float* ln_g   = (const float*)d_in[4];
    const float* ln_b   = (const float*)d_in[5];
    const float* W_coop = (const float*)d_in[6];
    const float* as_c   = (const float*)d_in[7];
    const float* ad_c   = (const float*)d_in[8];
    const float* W_conf = (const float*)d_in[9];
    const float* as_f   = (const float*)d_in[10];
    const float* ad_f   = (const float*)d_in[11];
    const float* W_self = (const float*)d_in[12];
    const float* W_neigh= (const float*)d_in[13];
    const float* b_sage = (const float*)d_in[14];
    const float* Wx_f   = (const float*)d_in[15];
    const float* Wh_f   = (const float*)d_in[16];
    const float* bx_f   = (const float*)d_in[17];
    const float* bh_f   = (const float*)d_in[18];
    const float* Wx_b   = (const float*)d_in[19];
    const float* Wh_b   = (const float*)d_in[20];
    const float* bx_b   = (const float*)d_in[21];
    const float* bh_b   = (const float*)d_in[22];
    const float* adj_coop = (const float*)d_in[23];
    const float* adj_conf = (const float*)d_in[24];
    const int*   mask   = (const int*)d_in[25];
    float* out = (float*)d_out;

    unsigned short* bfrag = (unsigned short*)((char*)d_ws + OFF_BFRAG);
    int*            adjm  = (int*)((char*)d_ws + OFF_ADJ);
    unsigned short* sfrag = (unsigned short*)((char*)d_ws + OFF_SFRAG);
    unsigned short* emb   = (unsigned short*)((char*)d_ws + OFF_EMB);
    float*          pooled= (float*)((char*)d_ws + OFF_POOLED);

    prep_kernel<<<32, 256, 0, stream>>>(W_coop, as_c, ad_c, W_conf, as_f, ad_f,
                                        W_self, W_neigh, adj_coop, adj_conf,
                                        bfrag, adjm, sfrag);
    gat_kernel<<<GTOT / 4, 256, 0, stream>>>(self_feat, nbr_feat, W_in, b_in_, ln_g, ln_b,
                                             bfrag, adjm, emb);
    sage_kernel<<<(BB * TT) / 4, 256, 0, stream>>>(emb, mask, sfrag, b_sage, pooled);
    gru_kernel<<<BB / 4, 256, 0, stream>>>(pooled, emb,
        Wx_f, Wh_f, bx_f, bh_f, Wx_b, Wh_b, bx_b, bh_b, out);
}

// Round 7
// 293.621 us; speedup vs baseline: 7.8949x; 1.1290x over previous
//
#include <hip/hip_runtime.h>
#include <hip/hip_bf16.h>

#define BB 4096
#define TT 5
#define GTOT (BB * TT * 5)        // 102400 graphs; emb row = b*25 + t*5 + node

// workspace byte offsets (total ~57.8 MB; bf16 emb everywhere)
#define OFF_BFRAG  0              // 17408 bf16 = 34816 B (gat B-fragments)
#define OFF_ADJ    36864          // 32 ints (adj masks [2][16])
#define OFF_SFRAG  40960          // 32768 bf16 = 65536 B (sage B-fragments)
#define OFF_EMB    106496         // 102400*256 bf16 = 52428800 B
#define OFF_POOLED 52535296ULL    // 20480*64 f32 = 5242880 B

typedef __bf16 bf16x8_t __attribute__((ext_vector_type(8)));
typedef __bf16 bf16x2_t __attribute__((ext_vector_type(2)));
typedef short  s16x4_t  __attribute__((ext_vector_type(4)));
typedef float  f32x4_t  __attribute__((ext_vector_type(4)));

static __device__ __forceinline__ unsigned short f2bf(float v) {
    return __builtin_bit_cast(unsigned short, (__bf16)v);
}

// ---------------------------------------------------------------------------
// Prep: B-fragments for gat GEMM (17 tiles x 2 ksteps), sage GEMM
// (8 tiles x 8 ksteps), and adjacency bitmasks.
// ---------------------------------------------------------------------------
__global__ void prep_kernel(
    const float* __restrict__ W_coop, const float* __restrict__ as_c, const float* __restrict__ ad_c,
    const float* __restrict__ W_conf, const float* __restrict__ as_f, const float* __restrict__ ad_f,
    const float* __restrict__ W_self, const float* __restrict__ W_neigh,
    const float* __restrict__ adj_coop, const float* __restrict__ adj_conf,
    unsigned short* __restrict__ bfrag, int* __restrict__ adjm_g,
    unsigned short* __restrict__ sfrag)
{
    const int gtid = blockIdx.x * 256 + threadIdx.x;
    const int gstride = gridDim.x * 256;

    for (int idx = gtid; idx < 17408; idx += gstride) {
        int j = idx & 7, l = (idx >> 3) & 63;
        int rest = idx >> 9, ks = rest & 1, it = rest >> 1;
        int k = ks * 32 + ((l >> 4) << 3) + j;
        int n = it * 16 + (l & 15);
        float val;
        if (n < 256) {
            int p = n >> 5, o = n & 31, head = p & 3;
            const float* W = (p >> 2) ? W_conf : W_coop;
            val = W[(head * 64 + k) * 32 + o];
        } else {
            int c = n - 256, sd = c >> 3, p = c & 7;
            int gat = p >> 2, head = p & 3;
            const float* W = gat ? W_conf : W_coop;
            const float* a = sd ? (gat ? ad_f : ad_c) : (gat ? as_f : as_c);
            float s = 0.f;
            for (int o = 0; o < 32; ++o) s = fmaf(W[(head * 64 + k) * 32 + o], a[head * 32 + o], s);
            val = s;
        }
        bfrag[idx] = f2bf(val);
    }

    for (int idx = gtid; idx < 32768; idx += gstride) {
        int j = idx & 7, l = (idx >> 3) & 63;
        int rest = idx >> 9, ks = rest & 7, nt = rest >> 3;
        int k = ks * 32 + ((l >> 4) << 3) + j;
        int n = nt * 16 + (l & 15);
        float v = (n < 64) ? W_self[k * 64 + n] : W_neigh[k * 64 + (n - 64)];
        sfrag[idx] = f2bf(v);
    }

    if (gtid < 32) {
        int gat = gtid >> 4, n = gtid & 15;
        int m = 0;
        if (n < 12) {
            const float* adj = gat ? adj_conf : adj_coop;
            for (int c = 0; c < 12; ++c) if (adj[n * 12 + c] > 0.f) m |= (1 << c);
        }
        adjm_g[gtid] = m;
    }
}

// ---------------------------------------------------------------------------
// Kernel 1: GAT encoder. One wave per graph, 4 independent waves/block, no
// barriers. Coop softmax specialized to its 3-neighbor block structure;
// attn LDS trimmed to 12 rows; batched coalesced emb store via LDS scratch.
// ---------------------------------------------------------------------------
__global__ __launch_bounds__(256) void gat_kernel(
    const float* __restrict__ self_feat, const float* __restrict__ nbr_feat,
    const float* __restrict__ W_in, const float* __restrict__ b_in,
    const float* __restrict__ ln_g, const float* __restrict__ ln_b,
    const unsigned short* __restrict__ bfrag, const int* __restrict__ adjm_g,
    unsigned short* __restrict__ emb)
{
    __shared__ float          sc_sh[4][16][12];       // 3072 B; reused as store scratch
    __shared__ unsigned short attn_sh[4][8][12][20];  // 15360 B, rows padded to 40 B

    const int tid = threadIdx.x, wave = tid >> 6, lane = tid & 63;
    const int lg = lane >> 4, m = lane & 15;

    // ---- graph decode ----
    const int g = blockIdx.x * 4 + wave;
    const int b = g / 25, r_ = g % 25, t = r_ / 5, node = r_ % 5;
    const float* x = (node == 0) ? (self_feat + (size_t)(b * 5 + t) * 48)
                                 : (nbr_feat + (size_t)((b * 4 + (node - 1)) * 5 + t) * 48);

    // ---- h[m][k] in A-fragment layout: k = ks*32 + lg*8 + j ----
    float hr[2][8];
    {
        float4 xv = make_float4(0.f, 0.f, 0.f, 0.f);
        if (m < 12) xv = *(const float4*)(x + m * 4);
        const float xc[4] = {xv.x, xv.y, xv.z, xv.w};
        #pragma unroll
        for (int ks = 0; ks < 2; ++ks) {
            const int k0 = ks * 32 + lg * 8;
            float4 bv0 = *(const float4*)(b_in + k0);
            float4 bv1 = *(const float4*)(b_in + k0 + 4);
            hr[ks][0] = bv0.x; hr[ks][1] = bv0.y; hr[ks][2] = bv0.z; hr[ks][3] = bv0.w;
            hr[ks][4] = bv1.x; hr[ks][5] = bv1.y; hr[ks][6] = bv1.z; hr[ks][7] = bv1.w;
            #pragma unroll
            for (int c = 0; c < 4; ++c) {
                float4 w0 = *(const float4*)(W_in + c * 64 + k0);
                float4 w1 = *(const float4*)(W_in + c * 64 + k0 + 4);
                hr[ks][0] = fmaf(xc[c], w0.x, hr[ks][0]);
                hr[ks][1] = fmaf(xc[c], w0.y, hr[ks][1]);
                hr[ks][2] = fmaf(xc[c], w0.z, hr[ks][2]);
                hr[ks][3] = fmaf(xc[c], w0.w, hr[ks][3]);
                hr[ks][4] = fmaf(xc[c], w1.x, hr[ks][4]);
                hr[ks][5] = fmaf(xc[c], w1.y, hr[ks][5]);
                hr[ks][6] = fmaf(xc[c], w1.z, hr[ks][6]);
                hr[ks][7] = fmaf(xc[c], w1.w, hr[ks][7]);
            }
        }
    }

    // ---- LayerNorm: 2-step butterfly over the 4 lanes sharing row m ----
    float s = 0.f, q = 0.f;
    #pragma unroll
    for (int ks = 0; ks < 2; ++ks)
        #pragma unroll
        for (int j = 0; j < 8; ++j) { s += hr[ks][j]; q = fmaf(hr[ks][j], hr[ks][j], q); }
    s += __shfl_xor(s, 16, 64); s += __shfl_xor(s, 32, 64);
    q += __shfl_xor(q, 16, 64); q += __shfl_xor(q, 32, 64);
    const float mu = s * (1.f / 64.f);
    const float rstd = rsqrtf(fmaxf(q * (1.f / 64.f) - mu * mu, 0.f) + 1e-5f);
    const float keep = (m < 12) ? 1.f : 0.f;

    bf16x8_t afrag[2];
    #pragma unroll
    for (int ks = 0; ks < 2; ++ks) {
        const int k0 = ks * 32 + lg * 8;
        float4 g0 = *(const float4*)(ln_g + k0);
        float4 g1 = *(const float4*)(ln_g + k0 + 4);
        float4 lb0 = *(const float4*)(ln_b + k0);
        float4 lb1 = *(const float4*)(ln_b + k0 + 4);
        const float gg[8] = {g0.x, g0.y, g0.z, g0.w, g1.x, g1.y, g1.z, g1.w};
        const float bb[8] = {lb0.x, lb0.y, lb0.z, lb0.w, lb1.x, lb1.y, lb1.z, lb1.w};
        #pragma unroll
        for (int j = 0; j < 8; ++j) {
            float v = fmaf((hr[ks][j] - mu) * rstd, gg[j], bb[j]);
            v = fmaxf(v, 0.f) * keep;                 // ReLU; zero junk rows 12-15
            afrag[ks][j] = (__bf16)v;
        }
    }

    // ---- scores tile (it=16) first: sc[col=m][node row] ----
    {
        f32x4_t acc16 = (f32x4_t){0.f, 0.f, 0.f, 0.f};
        #pragma unroll
        for (int ks = 0; ks < 2; ++ks) {
            bf16x8_t bfr = *(const bf16x8_t*)&bfrag[(size_t)((32 + ks) * 64 + lane) * 8];
            acc16 = __builtin_amdgcn_mfma_f32_16x16x32_bf16(afrag[ks], bfr, acc16, 0, 0, 0);
        }
        if (lg < 3) {
            #pragma unroll
            for (int r = 0; r < 4; ++r) sc_sh[wave][m][lg * 4 + r] = acc16[r];
        }
    }
    __asm__ volatile("" ::: "memory");

    // ---- softmax pass 1: coop pairs p=0..3 (exactly 3 contiguous neighbors) ----
    {
        const int tp = __float2int_rz((float)lane * 0.083334f);   // lane/12
        const int tn = lane - tp * 12;
        if (lane < 48) {
            float ssrc = sc_sh[wave][tp][tn];
            int am = adjm_g[tn];                       // = 7 << 3a
            int i0 = __builtin_ctz(am);                // 3a in {0,3,6,9}
            const float* dp = &sc_sh[wave][8 + tp][0];
            float d0 = dp[i0], d1 = dp[i0 + 1], d2 = dp[i0 + 2];
            float t0 = ssrc + d0; t0 = fmaxf(t0, 0.2f * t0);
            float t1 = ssrc + d1; t1 = fmaxf(t1, 0.2f * t1);
            float t2 = ssrc + d2; t2 = fmaxf(t2, 0.2f * t2);
            float e0 = __expf(t0), e1 = __expf(t1), e2 = __expf(t2);
            float inv = 1.f / (e0 + e1 + e2);
            float p0 = e0 * inv, p1 = e1 * inv, p2 = e2 * inv;
            bf16x2_t le, he, lo_, ho_;
            le[0] = (__bf16)p0;  le[1] = (__bf16)p1;
            he[0] = (__bf16)p2;  he[1] = (__bf16)0.f;
            lo_[0] = (__bf16)0.f; lo_[1] = (__bf16)p0;
            ho_[0] = (__bf16)p1;  ho_[1] = (__bf16)p2;
            bool odd = (i0 & 1);
            unsigned int wlo = __builtin_bit_cast(unsigned int, odd ? lo_ : le);
            unsigned int whi = __builtin_bit_cast(unsigned int, odd ? ho_ : he);
            int wd = i0 >> 1;                          // {0,1,3,4}
            unsigned int* rowp = (unsigned int*)&attn_sh[wave][tp][tn][0];
            const uint2 z2 = make_uint2(0u, 0u);
            ((uint2*)rowp)[0] = z2; ((uint2*)rowp)[1] = z2;
            ((uint2*)rowp)[2] = z2; ((uint2*)rowp)[3] = z2;   // dwords 0-7
            rowp[wd] = wlo; rowp[wd + 1] = whi;
        }
    }
    // ---- softmax pass 2: conf pairs p=4..7 (generic 12-wide masked) ----
    {
        const int tq = __float2int_rz((float)lane * 0.083334f);
        const int tn = lane - tq * 12;
        const int tp = 4 + tq;
        if (lane < 48) {
            float ssrc = sc_sh[wave][tp][tn];
            float4 d0 = *(const float4*)&sc_sh[wave][8 + tp][0];
            float4 d1 = *(const float4*)&sc_sh[wave][8 + tp][4];
            float4 d2 = *(const float4*)&sc_sh[wave][8 + tp][8];
            float dm[12] = {d0.x, d0.y, d0.z, d0.w, d1.x, d1.y, d1.z, d1.w, d2.x, d2.y, d2.z, d2.w};
            int am = adjm_g[16 + tn];
            float pr[12]; float ssum = 0.f;
            #pragma unroll
            for (int mm = 0; mm < 12; ++mm) {
                float tv = ssrc + dm[mm];
                tv = fmaxf(tv, 0.2f * tv);                 // leaky_relu(0.2)
                float pp = ((am >> mm) & 1) ? __expf(tv) : 0.f;
                ssum += pp; pr[mm] = pp;
            }
            float inv = 1.f / ssum;
            unsigned int w[6];
            #pragma unroll
            for (int qq = 0; qq < 6; ++qq) {
                bf16x2_t pk;
                pk[0] = (__bf16)(pr[2 * qq] * inv);
                pk[1] = (__bf16)(pr[2 * qq + 1] * inv);
                w[qq] = __builtin_bit_cast(unsigned int, pk);
            }
            uint2* arow = (uint2*)&attn_sh[wave][tp][tn][0];
            arow[0] = make_uint2(w[0], w[1]);
            arow[1] = make_uint2(w[2], w[3]);
            arow[2] = make_uint2(w[4], w[5]);
            arow[3] = make_uint2(0u, 0u);                  // cols 12-15 (read by PV lg=3)
        }
    }
    __asm__ volatile("" ::: "memory");

    // ---- fused main-GEMM + PV, streaming one 16-col tile at a time ----
    const int mrow = (m < 12) ? m : 11;                    // clamp: rows 12-15 removed
    const float presc = (lg == 3) ? 0.f : (1.f / 12.f);    // kill garbage C rows 12-15
    unsigned short* scratch = (unsigned short*)&sc_sh[wave][0][0];  // 768 B >= 512 B
    const f32x4_t zero4 = (f32x4_t){0.f, 0.f, 0.f, 0.f};
    #pragma unroll
    for (int p = 0; p < 8; ++p) {
        s16x4_t afr = *(const s16x4_t*)&attn_sh[wave][p][mrow][lg << 2];
        #pragma unroll
        for (int tt = 0; tt < 2; ++tt) {
            const int it = p * 2 + tt;
            f32x4_t acc = (f32x4_t){0.f, 0.f, 0.f, 0.f};
            #pragma unroll
            for (int ks = 0; ks < 2; ++ks) {
                bf16x8_t bfr = *(const bf16x8_t*)&bfrag[(size_t)((it * 2 + ks) * 64 + lane) * 8];
                acc = __builtin_amdgcn_mfma_f32_16x16x32_bf16(afrag[ks], bfr, acc, 0, 0, 0);
            }
            bf16x2_t bv0, bv1;
            bv0[0] = (__bf16)acc[0]; bv0[1] = (__bf16)acc[1];
            bv1[0] = (__bf16)acc[2]; bv1[1] = (__bf16)acc[3];
            s16x4_t bfr2;
            bfr2[0] = (short)__builtin_bit_cast(unsigned int, bv0);
            bfr2[1] = (short)(__builtin_bit_cast(unsigned int, bv0) >> 16);
            bfr2[2] = (short)__builtin_bit_cast(unsigned int, bv1);
            bfr2[3] = (short)(__builtin_bit_cast(unsigned int, bv1) >> 16);
            f32x4_t pv = __builtin_amdgcn_mfma_f32_16x16x16bf16_1k(afr, bfr2, zero4, 0, 0, 0);
            float ss = 0.f;
            #pragma unroll
            for (int r = 0; r < 4; ++r) {
                float xv = pv[r];
                xv = (xv > 0.f) ? xv : (__expf(xv) - 1.f);  // ELU
                ss += xv;
            }
            ss *= presc;                                    // zero lg=3 + 1/12 scale
            ss += __shfl_xor(ss, 16, 64);
            ss += __shfl_xor(ss, 32, 64);
            scratch[p * 32 + tt * 16 + m] = f2bf(ss);       // all lanes; dups same value
        }
    }
    __asm__ volatile("" ::: "memory");
    {
        uint2 v = *(const uint2*)&scratch[lane * 4];
        *(uint2*)&emb[(size_t)g * 256 + lane * 4] = v;      // coalesced 512 B/graph
    }
}

// ---------------------------------------------------------------------------
// Kernel 2: GraphSAGE via MFMA. One wave per (b,t): Y[16x128] = X[16x256]@Wsn,
// A-frags loaded directly from emb in fragment layout; combine in-wave.
// ---------------------------------------------------------------------------
__global__ __launch_bounds__(256) void sage_kernel(
    const unsigned short* __restrict__ emb, const int* __restrict__ mask,
    const unsigned short* __restrict__ sfrag, const float* __restrict__ b_sage,
    float* __restrict__ pooled)
{
    __shared__ float y_sh[4][5][128];                 // 10240 B
    const int tid = threadIdx.x, wave = tid >> 6, lane = tid & 63;
    const int bt = blockIdx.x * 4 + wave;             // 0..20479
    const int b = bt / 5;
    const int lg = lane >> 4, row = lane & 15;

    bf16x8_t afr[8];
    if (row < 5) {
        const unsigned short* base = emb + (size_t)(bt * 5 + row) * 256 + lg * 8;
        #pragma unroll
        for (int ks = 0; ks < 8; ++ks) afr[ks] = *(const bf16x8_t*)(base + ks * 32);
    } else {
        #pragma unroll
        for (int ks = 0; ks < 8; ++ks) {
            uint4 z = make_uint4(0u, 0u, 0u, 0u);
            afr[ks] = __builtin_bit_cast(bf16x8_t, z);
        }
    }

    #pragma unroll
    for (int nt = 0; nt < 8; ++nt) {
        f32x4_t acc = (f32x4_t){0.f, 0.f, 0.f, 0.f};
        #pragma unroll
        for (int ks = 0; ks < 8; ++ks) {
            bf16x8_t bfr = *(const bf16x8_t*)&sfrag[(size_t)((nt * 8 + ks) * 64 + lane) * 8];
            acc = __builtin_amdgcn_mfma_f32_16x16x32_bf16(afr[ks], bfr, acc, 0, 0, 0);
        }
        #pragma unroll
        for (int r = 0; r < 4; ++r) {
            int rw = lg * 4 + r;
            if (rw < 5) y_sh[wave][rw][nt * 16 + row] = acc[r];
        }
    }
    __asm__ volatile("" ::: "memory");

    float md[4];
    #pragma unroll
    for (int d = 0; d < 4; ++d) md[d] = (float)mask[b * 4 + d];
    const float degs = fmaxf(md[0] + md[1] + md[2] + md[3], 1.f);

    float dS[5], dN[5];
    #pragma unroll
    for (int n = 0; n < 5; ++n) {
        dS[n] = y_sh[wave][n][lane];
        dN[n] = y_sh[wave][n][64 + lane];
    }
    const float bsg = b_sage[lane];
    float agg0 = (md[0] * dN[1] + md[1] * dN[2] + md[2] * dN[3] + md[3] * dN[4]) / degs;
    float p = fmaxf(dS[0] + agg0 + bsg, 0.f);
    #pragma unroll
    for (int d = 0; d < 4; ++d)
        p += fmaxf(dS[d + 1] + md[d] * dN[0] + bsg, 0.f);

    pooled[(size_t)bt * 64 + lane] = p * 0.2f;
}

// ---------------------------------------------------------------------------
// Kernel 3: bidirectional GRU (lanes 0-31 fwd, 32-63 bwd) + output assembly.
// ---------------------------------------------------------------------------
__global__ __launch_bounds__(256) void gru_kernel(
    const float* __restrict__ pooled, const unsigned short* __restrict__ emb,
    const float* __restrict__ Wx_f, const float* __restrict__ Wh_f,
    const float* __restrict__ bx_f, const float* __restrict__ bh_f,
    const float* __restrict__ Wx_b, const float* __restrict__ Wh_b,
    const float* __restrict__ bx_b, const float* __restrict__ bh_b,
    float* __restrict__ out)
{
    __shared__ float x_sh[4][5][64];
    __shared__ float h_sh[4][2][32];
    const int tid = threadIdx.x, wave = tid >> 6, lane = tid & 63;
    const int b = blockIdx.x * 4 + wave;

    #pragma unroll
    for (int t = 0; t < 5; ++t) x_sh[wave][t][lane] = pooled[(size_t)(b * 5 + t) * 64 + lane];

    const int j = lane & 31, dir = lane >> 5;
    const float* Wx = dir ? Wx_b : Wx_f;
    const float* Wh = dir ? Wh_b : Wh_f;
    const float* bx = dir ? bx_b : bx_f;
    const float* bh = dir ? bh_b : bh_f;
    const float bxr = bx[j], bxz = bx[32 + j], bxn = bx[64 + j];
    const float bhr = bh[j], bhz = bh[32 + j], bhn = bh[64 + j];
    float h = 0.f;
    __syncthreads();

    for (int s = 0; s < 5; ++s) {
        const int t = dir ? (4 - s) : s;
        h_sh[wave][dir][j] = h;
        __syncthreads();
        float xr = bxr, xz = bxz, xn = bxn;
        for (int f = 0; f < 64; ++f) {
            float xv = x_sh[wave][t][f];
            xr = fmaf(xv, Wx[f * 96 + j], xr);
            xz = fmaf(xv, Wx[f * 96 + 32 + j], xz);
            xn = fmaf(xv, Wx[f * 96 + 64 + j], xn);
        }
        float hr = bhr, hz = bhz, hn = bhn;
        for (int f = 0; f < 32; ++f) {
            float hv = h_sh[wave][dir][f];
            hr = fmaf(hv, Wh[f * 96 + j], hr);
            hz = fmaf(hv, Wh[f * 96 + 32 + j], hz);
            hn = fmaf(hv, Wh[f * 96 + 64 + j], hn);
        }
        float rr = 1.f / (1.f + __expf(-(xr + hr)));
        float zz = 1.f / (1.f + __expf(-(xz + hz)));
        float ni = xn + rr * hn;
        ni = fminf(fmaxf(ni, -15.f), 15.f);
        float e2 = __expf(2.f * ni);
        float nn = (e2 - 1.f) / (e2 + 1.f);
        h = (1.f - zz) * nn + zz * h;
        __syncthreads();
    }

    out[(size_t)b * 320 + 256 + dir * 32 + j] = h;
    const unsigned short* se = emb + (size_t)((b * 5 + 4) * 5) * 256;
    #pragma unroll
    for (int c = 0; c < 4; ++c)
        out[(size_t)b * 320 + c * 64 + lane] = __builtin_bit_cast(float, ((unsigned int)se[c * 64 + lane]) << 16);
}

// ---------------------------------------------------------------------------
extern "C" void kernel_launch(void* const* d_in, const int* in_sizes, int n_in,
                              void* d_out, int out_size, void* d_ws, size_t ws_size,
                              hipStream_t stream) {
    (void)in_sizes; (void)n_in; (void)out_size; (void)ws_size;
    const float* self_feat = (const float*)d_in[0];
    const float* nbr_feat  = (const float*)d_in[1];
    const float* W_in   = (const float*)d_in[2];
    const float* b_in_  = (const float*)d_in[3];
    const float* ln_g   = (const float*)d_in[4];
    const float* ln_b   = (const float*)d_in[5];
    const float* W_coop = (const float*)d_in[6];
    const float* as_c   = (const float*)d_in[7];
    const float* ad_c   = (const float*)d_in[8];
    const float* W_conf = (const float*)d_in[9];
    const float* as_f   = (const float*)d_in[10];
    const float* ad_f   = (const float*)d_in[11];
    const float* W_self = (const float*)d_in[12];
    const float* W_neigh= (const float*)d_in[13];
    const float* b_sage = (const float*)d_in[14];
    const float* Wx_f   = (const float*)d_in[15];
    const float* Wh_f   = (const float*)d_in[16];
    const float* bx_f   = (const float*)d_in[17];
    const float* bh_f   = (const float*)d_in[18];
    const float* Wx_b   = (const float*)d_in[19];
    const float* Wh_b   = (const float*)d_in[20];
    const float* bx_b   = (const float*)d_in[21];
    const float* bh_b   = (const float*)d_in[22];
    const float* adj_coop = (const float*)d_in[23];
    const float* adj_conf = (const float*)d_in[24];
    const int*   mask   = (const int*)d_in[25];
    float* out = (float*)d_out;

    unsigned short* bfrag = (unsigned short*)((char*)d_ws + OFF_BFRAG);
    int*            adjm  = (int*)((char*)d_ws + OFF_ADJ);
    unsigned short* sfrag = (unsigned short*)((char*)d_ws + OFF_SFRAG);
    unsigned short* emb   = (unsigned short*)((char*)d_ws + OFF_EMB);
    float*          pooled= (float*)((char*)d_ws + OFF_POOLED);

    prep_kernel<<<32, 256, 0, stream>>>(W_coop, as_c, ad_c, W_conf, as_f, ad_f,
                                        W_self, W_neigh, adj_coop, adj_conf,
                                        bfrag, adjm, sfrag);
    gat_kernel<<<GTOT / 4, 256, 0, stream>>>(self_feat, nbr_feat, W_in, b_in_, ln_g, ln_b,
                                             bfrag, adjm, emb);
    sage_kernel<<<(BB * TT) / 4, 256, 0, stream>>>(emb, mask, sfrag, b_sage, pooled);
    gru_kernel<<<BB / 4, 256, 0, stream>>>(pooled, emb,
        Wx_f, Wh_f, bx_f, bh_f, Wx_b, Wh_b, bx_b, bh_b, out);
}

// Round 8
// 285.908 us; speedup vs baseline: 8.1078x; 1.0270x over previous
//
#include <hip/hip_runtime.h>
#include <hip/hip_bf16.h>

#define BB 4096
#define TT 5
#define GTOT (BB * TT * 5)        // 102400 graphs; emb row = b*25 + t*5 + node

// workspace byte offsets (total ~57.8 MB; bf16 emb everywhere)
#define OFF_BFRAG  0              // 17408 bf16 = 34816 B (gat B-fragments)
#define OFF_ADJ    36864          // 32 ints (unused by gat now; kept for layout)
#define OFF_SFRAG  40960          // 32768 bf16 = 65536 B (sage B-fragments)
#define OFF_EMB    106496         // 102400*256 bf16 = 52428800 B
#define OFF_POOLED 52535296ULL    // 20480*64 f32 = 5242880 B

typedef __bf16 bf16x8_t __attribute__((ext_vector_type(8)));
typedef __bf16 bf16x4_t __attribute__((ext_vector_type(4)));
typedef __bf16 bf16x2_t __attribute__((ext_vector_type(2)));
typedef short  s16x4_t  __attribute__((ext_vector_type(4)));
typedef float  f32x4_t  __attribute__((ext_vector_type(4)));
typedef float  f32x2_t  __attribute__((ext_vector_type(2)));

static __device__ __forceinline__ unsigned short f2bf(float v) {
    return __builtin_bit_cast(unsigned short, (__bf16)v);
}

// ---------------------------------------------------------------------------
// Prep: B-fragments for gat GEMM (17 tiles x 2 ksteps), sage GEMM
// (8 tiles x 8 ksteps), and adjacency bitmasks (legacy, unused).
// ---------------------------------------------------------------------------
__global__ void prep_kernel(
    const float* __restrict__ W_coop, const float* __restrict__ as_c, const float* __restrict__ ad_c,
    const float* __restrict__ W_conf, const float* __restrict__ as_f, const float* __restrict__ ad_f,
    const float* __restrict__ W_self, const float* __restrict__ W_neigh,
    const float* __restrict__ adj_coop, const float* __restrict__ adj_conf,
    unsigned short* __restrict__ bfrag, int* __restrict__ adjm_g,
    unsigned short* __restrict__ sfrag)
{
    const int gtid = blockIdx.x * 256 + threadIdx.x;
    const int gstride = gridDim.x * 256;

    for (int idx = gtid; idx < 17408; idx += gstride) {
        int j = idx & 7, l = (idx >> 3) & 63;
        int rest = idx >> 9, ks = rest & 1, it = rest >> 1;
        int k = ks * 32 + ((l >> 4) << 3) + j;
        int n = it * 16 + (l & 15);
        float val;
        if (n < 256) {
            int p = n >> 5, o = n & 31, head = p & 3;
            const float* W = (p >> 2) ? W_conf : W_coop;
            val = W[(head * 64 + k) * 32 + o];
        } else {
            int c = n - 256, sd = c >> 3, p = c & 7;
            int gat = p >> 2, head = p & 3;
            const float* W = gat ? W_conf : W_coop;
            const float* a = sd ? (gat ? ad_f : ad_c) : (gat ? as_f : as_c);
            float s = 0.f;
            for (int o = 0; o < 32; ++o) s = fmaf(W[(head * 64 + k) * 32 + o], a[head * 32 + o], s);
            val = s;
        }
        bfrag[idx] = f2bf(val);
    }

    for (int idx = gtid; idx < 32768; idx += gstride) {
        int j = idx & 7, l = (idx >> 3) & 63;
        int rest = idx >> 9, ks = rest & 7, nt = rest >> 3;
        int k = ks * 32 + ((l >> 4) << 3) + j;
        int n = nt * 16 + (l & 15);
        float v = (n < 64) ? W_self[k * 64 + n] : W_neigh[k * 64 + (n - 64)];
        sfrag[idx] = f2bf(v);
    }

    if (gtid < 32) {
        int gat = gtid >> 4, n = gtid & 15;
        int m = 0;
        if (n < 12) {
            const float* adj = gat ? adj_conf : adj_coop;
            for (int c = 0; c < 12; ++c) if (adj[n * 12 + c] > 0.f) m |= (1 << c);
        }
        adjm_g[gtid] = m;
    }
}

// ---------------------------------------------------------------------------
// Kernel 1: GAT encoder. One wave per graph, 4 independent waves/block, no
// barriers. Packed-f32 h/LN math; arithmetic adjacency (no mask loads);
// streamed main-GEMM+PV; batched coalesced emb store.
// ---------------------------------------------------------------------------
__global__ __launch_bounds__(256) void gat_kernel(
    const float* __restrict__ self_feat, const float* __restrict__ nbr_feat,
    const float* __restrict__ W_in, const float* __restrict__ b_in,
    const float* __restrict__ ln_g, const float* __restrict__ ln_b,
    const unsigned short* __restrict__ bfrag,
    unsigned short* __restrict__ emb)
{
    __shared__ float          sc_sh[4][16][12];       // 3072 B; reused as store scratch
    __shared__ unsigned short attn_sh[4][8][12][20];  // 15360 B, rows padded to 40 B

    const int tid = threadIdx.x, wave = tid >> 6, lane = tid & 63;
    const int lg = lane >> 4, m = lane & 15;

    // ---- graph decode ----
    const int g = blockIdx.x * 4 + wave;
    const int b = g / 25, r_ = g % 25, t = r_ / 5, node = r_ % 5;
    const float* x = (node == 0) ? (self_feat + (size_t)(b * 5 + t) * 48)
                                 : (nbr_feat + (size_t)((b * 4 + (node - 1)) * 5 + t) * 48);

    // ---- h[m][k] in A-fragment layout (packed f32 pairs): k = ks*32+lg*8+j ----
    f32x2_t hr2[2][4];
    {
        float4 xv = make_float4(0.f, 0.f, 0.f, 0.f);
        if (m < 12) xv = *(const float4*)(x + m * 4);
        const float xc[4] = {xv.x, xv.y, xv.z, xv.w};
        #pragma unroll
        for (int ks = 0; ks < 2; ++ks) {
            const int k0 = ks * 32 + lg * 8;
            float4 bv0 = *(const float4*)(b_in + k0);
            float4 bv1 = *(const float4*)(b_in + k0 + 4);
            hr2[ks][0] = (f32x2_t){bv0.x, bv0.y};
            hr2[ks][1] = (f32x2_t){bv0.z, bv0.w};
            hr2[ks][2] = (f32x2_t){bv1.x, bv1.y};
            hr2[ks][3] = (f32x2_t){bv1.z, bv1.w};
            #pragma unroll
            for (int c = 0; c < 4; ++c) {
                float4 w0 = *(const float4*)(W_in + c * 64 + k0);
                float4 w1 = *(const float4*)(W_in + c * 64 + k0 + 4);
                f32x2_t xb = (f32x2_t){xc[c], xc[c]};
                hr2[ks][0] = __builtin_elementwise_fma(xb, (f32x2_t){w0.x, w0.y}, hr2[ks][0]);
                hr2[ks][1] = __builtin_elementwise_fma(xb, (f32x2_t){w0.z, w0.w}, hr2[ks][1]);
                hr2[ks][2] = __builtin_elementwise_fma(xb, (f32x2_t){w1.x, w1.y}, hr2[ks][2]);
                hr2[ks][3] = __builtin_elementwise_fma(xb, (f32x2_t){w1.z, w1.w}, hr2[ks][3]);
            }
        }
    }

    // ---- LayerNorm: packed partials + 2-step butterfly over 4 lanes/row ----
    f32x2_t s2 = (f32x2_t){0.f, 0.f}, q2 = (f32x2_t){0.f, 0.f};
    #pragma unroll
    for (int ks = 0; ks < 2; ++ks)
        #pragma unroll
        for (int tJ = 0; tJ < 4; ++tJ) {
            s2 = s2 + hr2[ks][tJ];
            q2 = __builtin_elementwise_fma(hr2[ks][tJ], hr2[ks][tJ], q2);
        }
    float s = s2[0] + s2[1], q = q2[0] + q2[1];
    s += __shfl_xor(s, 16, 64); s += __shfl_xor(s, 32, 64);
    q += __shfl_xor(q, 16, 64); q += __shfl_xor(q, 32, 64);
    const float mu = s * (1.f / 64.f);
    const float rstd = rsqrtf(fmaxf(q * (1.f / 64.f) - mu * mu, 0.f) + 1e-5f);
    const float keep = (m < 12) ? 1.f : 0.f;
    const f32x2_t mu2 = (f32x2_t){mu, mu};
    const f32x2_t rk2 = (f32x2_t){rstd * keep, rstd * keep};
    const f32x2_t z22 = (f32x2_t){0.f, 0.f};

    bf16x8_t afrag[2];
    #pragma unroll
    for (int ks = 0; ks < 2; ++ks) {
        const int k0 = ks * 32 + lg * 8;
        float4 g0 = *(const float4*)(ln_g + k0);
        float4 g1 = *(const float4*)(ln_g + k0 + 4);
        float4 lb0 = *(const float4*)(ln_b + k0);
        float4 lb1 = *(const float4*)(ln_b + k0 + 4);
        f32x2_t gp[4] = {{g0.x, g0.y}, {g0.z, g0.w}, {g1.x, g1.y}, {g1.z, g1.w}};
        f32x2_t bp[4] = {{lb0.x, lb0.y}, {lb0.z, lb0.w}, {lb1.x, lb1.y}, {lb1.z, lb1.w}};
        const f32x2_t keep2 = (f32x2_t){keep, keep};
        #pragma unroll
        for (int tJ = 0; tJ < 4; ++tJ) {
            f32x2_t rg = gp[tJ] * rk2;                         // rstd*keep*gamma
            f32x2_t v2 = __builtin_elementwise_fma(hr2[ks][tJ] - mu2, rg, bp[tJ] * keep2);
            v2 = __builtin_elementwise_max(v2, z22);           // ReLU (junk rows -> 0)
            afrag[ks][2 * tJ]     = (__bf16)v2[0];
            afrag[ks][2 * tJ + 1] = (__bf16)v2[1];
        }
    }

    // ---- scores tile (it=16) first: sc[col=m][node row] ----
    {
        f32x4_t acc16 = (f32x4_t){0.f, 0.f, 0.f, 0.f};
        #pragma unroll
        for (int ks = 0; ks < 2; ++ks) {
            bf16x8_t bfr = *(const bf16x8_t*)&bfrag[(size_t)((32 + ks) * 64 + lane) * 8];
            acc16 = __builtin_amdgcn_mfma_f32_16x16x32_bf16(afrag[ks], bfr, acc16, 0, 0, 0);
        }
        if (lg < 3) {
            #pragma unroll
            for (int r = 0; r < 4; ++r) sc_sh[wave][m][lg * 4 + r] = acc16[r];
        }
    }
    __asm__ volatile("" ::: "memory");

    // ---- softmax pass 1: coop pairs p=0..3 (3 contiguous neighbors, i0=3a) ----
    {
        const int tp = __float2int_rz((float)lane * 0.083334f);   // lane/12
        const int tn = lane - tp * 12;
        const int ap = (tn * 11) >> 5;                            // tn/3
        if (lane < 48) {
            float ssrc = sc_sh[wave][tp][tn];
            int i0 = 3 * ap;                                      // {0,3,6,9}
            const float* dp = &sc_sh[wave][8 + tp][0];
            float d0 = dp[i0], d1 = dp[i0 + 1], d2 = dp[i0 + 2];
            float t0 = ssrc + d0; t0 = fmaxf(t0, 0.2f * t0);
            float t1 = ssrc + d1; t1 = fmaxf(t1, 0.2f * t1);
            float t2 = ssrc + d2; t2 = fmaxf(t2, 0.2f * t2);
            float e0 = __expf(t0), e1 = __expf(t1), e2 = __expf(t2);
            float inv = 1.f / (e0 + e1 + e2);
            float p0 = e0 * inv, p1 = e1 * inv, p2 = e2 * inv;
            bf16x2_t le, he, lo_, ho_;
            le[0] = (__bf16)p0;  le[1] = (__bf16)p1;
            he[0] = (__bf16)p2;  he[1] = (__bf16)0.f;
            lo_[0] = (__bf16)0.f; lo_[1] = (__bf16)p0;
            ho_[0] = (__bf16)p1;  ho_[1] = (__bf16)p2;
            bool odd = (i0 & 1);
            unsigned int wlo = __builtin_bit_cast(unsigned int, odd ? lo_ : le);
            unsigned int whi = __builtin_bit_cast(unsigned int, odd ? ho_ : he);
            int wd = i0 >> 1;                          // {0,1,3,4}
            unsigned int* rowp = (unsigned int*)&attn_sh[wave][tp][tn][0];
            const uint2 z2 = make_uint2(0u, 0u);
            ((uint2*)rowp)[0] = z2; ((uint2*)rowp)[1] = z2;
            ((uint2*)rowp)[2] = z2; ((uint2*)rowp)[3] = z2;   // dwords 0-7
            rowp[wd] = wlo; rowp[wd + 1] = whi;
        }
    }
    // ---- softmax pass 2: conf pairs p=4..7 (excluded = approach-mates\self) ----
    {
        const int tq = __float2int_rz((float)lane * 0.083334f);
        const int tn = lane - tq * 12;
        const int tp = 4 + tq;
        const int ap = (tn * 11) >> 5;
        const int am_inv = (7 << (3 * ap)) ^ (1 << tn);   // bit set = EXCLUDED
        if (lane < 48) {
            float ssrc = sc_sh[wave][tp][tn];
            float4 d0 = *(const float4*)&sc_sh[wave][8 + tp][0];
            float4 d1 = *(const float4*)&sc_sh[wave][8 + tp][4];
            float4 d2 = *(const float4*)&sc_sh[wave][8 + tp][8];
            float dm[12] = {d0.x, d0.y, d0.z, d0.w, d1.x, d1.y, d1.z, d1.w, d2.x, d2.y, d2.z, d2.w};
            float pr[12]; float ssum = 0.f;
            #pragma unroll
            for (int mm = 0; mm < 12; ++mm) {
                float tv = ssrc + dm[mm];
                tv = fmaxf(tv, 0.2f * tv);                 // leaky_relu(0.2)
                float pp = ((am_inv >> mm) & 1) ? 0.f : __expf(tv);
                ssum += pp; pr[mm] = pp;
            }
            float inv = 1.f / ssum;
            unsigned int w[6];
            #pragma unroll
            for (int qq = 0; qq < 6; ++qq) {
                bf16x2_t pk;
                pk[0] = (__bf16)(pr[2 * qq] * inv);
                pk[1] = (__bf16)(pr[2 * qq + 1] * inv);
                w[qq] = __builtin_bit_cast(unsigned int, pk);
            }
            uint2* arow = (uint2*)&attn_sh[wave][tp][tn][0];
            arow[0] = make_uint2(w[0], w[1]);
            arow[1] = make_uint2(w[2], w[3]);
            arow[2] = make_uint2(w[4], w[5]);
            arow[3] = make_uint2(0u, 0u);                  // cols 12-15 (read by PV lg=3)
        }
    }
    __asm__ volatile("" ::: "memory");

    // ---- fused main-GEMM + PV, streaming one 16-col tile at a time ----
    const int mrow = (m < 12) ? m : 11;                    // clamp: rows 12-15 removed
    const float presc = (lg == 3) ? 0.f : (1.f / 12.f);    // kill garbage C rows 12-15
    unsigned short* scratch = (unsigned short*)&sc_sh[wave][0][0];  // 768 B >= 512 B
    const f32x4_t zero4 = (f32x4_t){0.f, 0.f, 0.f, 0.f};
    #pragma unroll
    for (int p = 0; p < 8; ++p) {
        s16x4_t afr = *(const s16x4_t*)&attn_sh[wave][p][mrow][lg << 2];
        #pragma unroll
        for (int tt = 0; tt < 2; ++tt) {
            const int it = p * 2 + tt;
            f32x4_t acc = (f32x4_t){0.f, 0.f, 0.f, 0.f};
            #pragma unroll
            for (int ks = 0; ks < 2; ++ks) {
                bf16x8_t bfr = *(const bf16x8_t*)&bfrag[(size_t)((it * 2 + ks) * 64 + lane) * 8];
                acc = __builtin_amdgcn_mfma_f32_16x16x32_bf16(afrag[ks], bfr, acc, 0, 0, 0);
            }
            bf16x4_t bv;
            bv[0] = (__bf16)acc[0]; bv[1] = (__bf16)acc[1];
            bv[2] = (__bf16)acc[2]; bv[3] = (__bf16)acc[3];
            s16x4_t bfr2 = __builtin_bit_cast(s16x4_t, bv);
            f32x4_t pv = __builtin_amdgcn_mfma_f32_16x16x16bf16_1k(afr, bfr2, zero4, 0, 0, 0);
            float ss = 0.f;
            #pragma unroll
            for (int r = 0; r < 4; ++r) {
                float xv = pv[r];
                xv = (xv > 0.f) ? xv : (__expf(xv) - 1.f);  // ELU
                ss += xv;
            }
            ss *= presc;                                    // zero lg=3 + 1/12 scale
            ss += __shfl_xor(ss, 16, 64);
            ss += __shfl_xor(ss, 32, 64);
            scratch[p * 32 + tt * 16 + m] = f2bf(ss);       // all lanes; dups same value
        }
    }
    __asm__ volatile("" ::: "memory");
    {
        uint2 v = *(const uint2*)&scratch[lane * 4];
        *(uint2*)&emb[(size_t)g * 256 + lane * 4] = v;      // coalesced 512 B/graph
    }
}

// ---------------------------------------------------------------------------
// Kernel 2: GraphSAGE via MFMA, 2 graphs per wave (B-fragments loaded once,
// applied to both A operands -> halves L2 traffic for sfrag).
// ---------------------------------------------------------------------------
__global__ __launch_bounds__(256) void sage_kernel(
    const unsigned short* __restrict__ emb, const int* __restrict__ mask,
    const unsigned short* __restrict__ sfrag, const float* __restrict__ b_sage,
    float* __restrict__ pooled)
{
    __shared__ float y_sh[4][2][5][128];              // 20480 B
    const int tid = threadIdx.x, wave = tid >> 6, lane = tid & 63;
    const int widx = blockIdx.x * 4 + wave;           // 0..10239
    const int bt0 = widx * 2, bt1 = bt0 + 1;
    const int lg = lane >> 4, row = lane & 15;

    bf16x8_t afrA[8], afrB[8];
    {
        uint4 z = make_uint4(0u, 0u, 0u, 0u);
        if (row < 5) {
            const unsigned short* baseA = emb + (size_t)(bt0 * 5 + row) * 256 + lg * 8;
            const unsigned short* baseB = emb + (size_t)(bt1 * 5 + row) * 256 + lg * 8;
            #pragma unroll
            for (int ks = 0; ks < 8; ++ks) {
                afrA[ks] = *(const bf16x8_t*)(baseA + ks * 32);
                afrB[ks] = *(const bf16x8_t*)(baseB + ks * 32);
            }
        } else {
            #pragma unroll
            for (int ks = 0; ks < 8; ++ks) {
                afrA[ks] = __builtin_bit_cast(bf16x8_t, z);
                afrB[ks] = __builtin_bit_cast(bf16x8_t, z);
            }
        }
    }

    #pragma unroll
    for (int nt = 0; nt < 8; ++nt) {
        f32x4_t accA = (f32x4_t){0.f, 0.f, 0.f, 0.f};
        f32x4_t accB = (f32x4_t){0.f, 0.f, 0.f, 0.f};
        #pragma unroll
        for (int ks = 0; ks < 8; ++ks) {
            bf16x8_t bfr = *(const bf16x8_t*)&sfrag[(size_t)((nt * 8 + ks) * 64 + lane) * 8];
            accA = __builtin_amdgcn_mfma_f32_16x16x32_bf16(afrA[ks], bfr, accA, 0, 0, 0);
            accB = __builtin_amdgcn_mfma_f32_16x16x32_bf16(afrB[ks], bfr, accB, 0, 0, 0);
        }
        #pragma unroll
        for (int r = 0; r < 4; ++r) {
            int rw = lg * 4 + r;
            if (rw < 5) {
                y_sh[wave][0][rw][nt * 16 + row] = accA[r];
                y_sh[wave][1][rw][nt * 16 + row] = accB[r];
            }
        }
    }
    __asm__ volatile("" ::: "memory");

    const float bsg = b_sage[lane];
    #pragma unroll
    for (int gsel = 0; gsel < 2; ++gsel) {
        const int bt = gsel ? bt1 : bt0;
        const int b = bt / 5;
        float md[4];
        #pragma unroll
        for (int d = 0; d < 4; ++d) md[d] = (float)mask[b * 4 + d];
        const float degs = fmaxf(md[0] + md[1] + md[2] + md[3], 1.f);

        float dS[5], dN[5];
        #pragma unroll
        for (int n = 0; n < 5; ++n) {
            dS[n] = y_sh[wave][gsel][n][lane];
            dN[n] = y_sh[wave][gsel][n][64 + lane];
        }
        float agg0 = (md[0] * dN[1] + md[1] * dN[2] + md[2] * dN[3] + md[3] * dN[4]) / degs;
        float p = fmaxf(dS[0] + agg0 + bsg, 0.f);
        #pragma unroll
        for (int d = 0; d < 4; ++d)
            p += fmaxf(dS[d + 1] + md[d] * dN[0] + bsg, 0.f);

        pooled[(size_t)bt * 64 + lane] = p * 0.2f;
    }
}

// ---------------------------------------------------------------------------
// Kernel 3: bidirectional GRU (lanes 0-31 fwd, 32-63 bwd) + output assembly.
// ---------------------------------------------------------------------------
__global__ __launch_bounds__(256) void gru_kernel(
    const float* __restrict__ pooled, const unsigned short* __restrict__ emb,
    const float* __restrict__ Wx_f, const float* __restrict__ Wh_f,
    const float* __restrict__ bx_f, const float* __restrict__ bh_f,
    const float* __restrict__ Wx_b, const float* __restrict__ Wh_b,
    const float* __restrict__ bx_b, const float* __restrict__ bh_b,
    float* __restrict__ out)
{
    __shared__ float x_sh[4][5][64];
    __shared__ float h_sh[4][2][32];
    const int tid = threadIdx.x, wave = tid >> 6, lane = tid & 63;
    const int b = blockIdx.x * 4 + wave;

    #pragma unroll
    for (int t = 0; t < 5; ++t) x_sh[wave][t][lane] = pooled[(size_t)(b * 5 + t) * 64 + lane];

    const int j = lane & 31, dir = lane >> 5;
    const float* Wx = dir ? Wx_b : Wx_f;
    const float* Wh = dir ? Wh_b : Wh_f;
    const float* bx = dir ? bx_b : bx_f;
    const float* bh = dir ? bh_b : bh_f;
    const float bxr = bx[j], bxz = bx[32 + j], bxn = bx[64 + j];
    const float bhr = bh[j], bhz = bh[32 + j], bhn = bh[64 + j];
    float h = 0.f;
    __syncthreads();

    for (int s = 0; s < 5; ++s) {
        const int t = dir ? (4 - s) : s;
        h_sh[wave][dir][j] = h;
        __syncthreads();
        float xr = bxr, xz = bxz, xn = bxn;
        for (int f = 0; f < 64; ++f) {
            float xv = x_sh[wave][t][f];
            xr = fmaf(xv, Wx[f * 96 + j], xr);
            xz = fmaf(xv, Wx[f * 96 + 32 + j], xz);
            xn = fmaf(xv, Wx[f * 96 + 64 + j], xn);
        }
        float hr = bhr, hz = bhz, hn = bhn;
        for (int f = 0; f < 32; ++f) {
            float hv = h_sh[wave][dir][f];
            hr = fmaf(hv, Wh[f * 96 + j], hr);
            hz = fmaf(hv, Wh[f * 96 + 32 + j], hz);
            hn = fmaf(hv, Wh[f * 96 + 64 + j], hn);
        }
        float rr = 1.f / (1.f + __expf(-(xr + hr)));
        float zz = 1.f / (1.f + __expf(-(xz + hz)));
        float ni = xn + rr * hn;
        ni = fminf(fmaxf(ni, -15.f), 15.f);
        float e2 = __expf(2.f * ni);
        float nn = (e2 - 1.f) / (e2 + 1.f);
        h = (1.f - zz) * nn + zz * h;
        __syncthreads();
    }

    out[(size_t)b * 320 + 256 + dir * 32 + j] = h;
    const unsigned short* se = emb + (size_t)((b * 5 + 4) * 5) * 256;
    #pragma unroll
    for (int c = 0; c < 4; ++c)
        out[(size_t)b * 320 + c * 64 + lane] = __builtin_bit_cast(float, ((unsigned int)se[c * 64 + lane]) << 16);
}

// ---------------------------------------------------------------------------
extern "C" void kernel_launch(void* const* d_in, const int* in_sizes, int n_in,
                              void* d_out, int out_size, void* d_ws, size_t ws_size,
                              hipStream_t stream) {
    (void)in_sizes; (void)n_in; (void)out_size; (void)ws_size;
    const float* self_feat = (const float*)d_in[0];
    const float* nbr_feat  = (const float*)d_in[1];
    const float* W_in   = (const float*)d_in[2];
    const float* b_in_  = (const float*)d_in[3];
    const float* ln_g   = (const float*)d_in[4];
    const float* ln_b   = (const float*)d_in[5];
    const float* W_coop = (const float*)d_in[6];
    const float* as_c   = (const float*)d_in[7];
    const float* ad_c   = (const float*)d_in[8];
    const float* W_conf = (const float*)d_in[9];
    const float* as_f   = (const float*)d_in[10];
    const float* ad_f   = (const float*)d_in[11];
    const float* W_self = (const float*)d_in[12];
    const float* W_neigh= (const float*)d_in[13];
    const float* b_sage = (const float*)d_in[14];
    const float* Wx_f   = (const float*)d_in[15];
    const float* Wh_f   = (const float*)d_in[16];
    const float* bx_f   = (const float*)d_in[17];
    const float* bh_f   = (const float*)d_in[18];
    const float* Wx_b   = (const float*)d_in[19];
    const float* Wh_b   = (const float*)d_in[20];
    const float* bx_b   = (const float*)d_in[21];
    const float* bh_b   = (const float*)d_in[22];
    const float* adj_coop = (const float*)d_in[23];
    const float* adj_conf = (const float*)d_in[24];
    const int*   mask   = (const int*)d_in[25];
    float* out = (float*)d_out;

    unsigned short* bfrag = (unsigned short*)((char*)d_ws + OFF_BFRAG);
    int*            adjm  = (int*)((char*)d_ws + OFF_ADJ);
    unsigned short* sfrag = (unsigned short*)((char*)d_ws + OFF_SFRAG);
    unsigned short* emb   = (unsigned short*)((char*)d_ws + OFF_EMB);
    float*          pooled= (float*)((char*)d_ws + OFF_POOLED);

    prep_kernel<<<32, 256, 0, stream>>>(W_coop, as_c, ad_c, W_conf, as_f, ad_f,
                                        W_self, W_neigh, adj_coop, adj_conf,
                                        bfrag, adjm, sfrag);
    gat_kernel<<<GTOT / 4, 256, 0, stream>>>(self_feat, nbr_feat, W_in, b_in_, ln_g, ln_b,
                                             bfrag, emb);
    sage_kernel<<<(BB * TT) / 8, 256, 0, stream>>>(emb, mask, sfrag, b_sage, pooled);
    gru_kernel<<<BB / 4, 256, 0, stream>>>(pooled, emb,
        Wx_f, Wh_f, bx_f, bh_f, Wx_b, Wh_b, bx_b, bh_b, out);
}

// Round 9
// 273.558 us; speedup vs baseline: 8.4739x; 1.0451x over previous
//
#include <hip/hip_runtime.h>
#include <hip/hip_bf16.h>

#define BB 4096
#define TT 5
#define GTOT (BB * TT * 5)        // 102400 graphs; emb row = b*25 + t*5 + node

// workspace byte offsets (total ~57.8 MB; bf16 emb everywhere)
#define OFF_BFRAG  0              // 17408 bf16 = 34816 B (gat B-fragments)
#define OFF_ADJ    36864          // 32 ints (legacy, unused)
#define OFF_SFRAG  40960          // 32768 bf16 = 65536 B (sage B-fragments)
#define OFF_EMB    106496         // 102400*256 bf16 = 52428800 B
#define OFF_POOLED 52535296ULL    // 20480*64 f32 = 5242880 B

typedef __bf16 bf16x8_t __attribute__((ext_vector_type(8)));
typedef __bf16 bf16x2_t __attribute__((ext_vector_type(2)));
typedef short  s16x4_t  __attribute__((ext_vector_type(4)));
typedef float  f32x4_t  __attribute__((ext_vector_type(4)));

static __device__ __forceinline__ unsigned short f2bf(float v) {
    return __builtin_bit_cast(unsigned short, (__bf16)v);
}

// ---------------------------------------------------------------------------
// Prep: B-fragments for gat GEMM (17 tiles x 2 ksteps), sage GEMM
// (8 tiles x 8 ksteps).
// ---------------------------------------------------------------------------
__global__ void prep_kernel(
    const float* __restrict__ W_coop, const float* __restrict__ as_c, const float* __restrict__ ad_c,
    const float* __restrict__ W_conf, const float* __restrict__ as_f, const float* __restrict__ ad_f,
    const float* __restrict__ W_self, const float* __restrict__ W_neigh,
    unsigned short* __restrict__ bfrag, unsigned short* __restrict__ sfrag)
{
    const int gtid = blockIdx.x * 256 + threadIdx.x;
    const int gstride = gridDim.x * 256;

    for (int idx = gtid; idx < 17408; idx += gstride) {
        int j = idx & 7, l = (idx >> 3) & 63;
        int rest = idx >> 9, ks = rest & 1, it = rest >> 1;
        int k = ks * 32 + ((l >> 4) << 3) + j;
        int n = it * 16 + (l & 15);
        float val;
        if (n < 256) {
            int p = n >> 5, o = n & 31, head = p & 3;
            const float* W = (p >> 2) ? W_conf : W_coop;
            val = W[(head * 64 + k) * 32 + o];
        } else {
            int c = n - 256, sd = c >> 3, p = c & 7;
            int gat = p >> 2, head = p & 3;
            const float* W = gat ? W_conf : W_coop;
            const float* a = sd ? (gat ? ad_f : ad_c) : (gat ? as_f : as_c);
            float s = 0.f;
            for (int o = 0; o < 32; ++o) s = fmaf(W[(head * 64 + k) * 32 + o], a[head * 32 + o], s);
            val = s;
        }
        bfrag[idx] = f2bf(val);
    }

    for (int idx = gtid; idx < 32768; idx += gstride) {
        int j = idx & 7, l = (idx >> 3) & 63;
        int rest = idx >> 9, ks = rest & 7, nt = rest >> 3;
        int k = ks * 32 + ((l >> 4) << 3) + j;
        int n = nt * 16 + (l & 15);
        float v = (n < 64) ? W_self[k * 64 + n] : W_neigh[k * 64 + (n - 64)];
        sfrag[idx] = f2bf(v);
    }
}

// ---------------------------------------------------------------------------
// Kernel 1: GAT encoder (R7-proven form). One wave per graph, 4 independent
// waves/block, no barriers. Scalar h/LN; arithmetic adjacency (no mask
// loads); streamed main-GEMM+PV; batched coalesced emb store.
// ---------------------------------------------------------------------------
__global__ __launch_bounds__(256) void gat_kernel(
    const float* __restrict__ self_feat, const float* __restrict__ nbr_feat,
    const float* __restrict__ W_in, const float* __restrict__ b_in,
    const float* __restrict__ ln_g, const float* __restrict__ ln_b,
    const unsigned short* __restrict__ bfrag,
    unsigned short* __restrict__ emb)
{
    __shared__ float          sc_sh[4][16][12];       // 3072 B; reused as store scratch
    __shared__ unsigned short attn_sh[4][8][12][20];  // 15360 B, rows padded to 40 B

    const int tid = threadIdx.x, wave = tid >> 6, lane = tid & 63;
    const int lg = lane >> 4, m = lane & 15;

    // ---- graph decode ----
    const int g = blockIdx.x * 4 + wave;
    const int b = g / 25, r_ = g % 25, t = r_ / 5, node = r_ % 5;
    const float* x = (node == 0) ? (self_feat + (size_t)(b * 5 + t) * 48)
                                 : (nbr_feat + (size_t)((b * 4 + (node - 1)) * 5 + t) * 48);

    // ---- h[m][k] in A-fragment layout: k = ks*32 + lg*8 + j ----
    float hr[2][8];
    {
        float4 xv = make_float4(0.f, 0.f, 0.f, 0.f);
        if (m < 12) xv = *(const float4*)(x + m * 4);
        const float xc[4] = {xv.x, xv.y, xv.z, xv.w};
        #pragma unroll
        for (int ks = 0; ks < 2; ++ks) {
            const int k0 = ks * 32 + lg * 8;
            float4 bv0 = *(const float4*)(b_in + k0);
            float4 bv1 = *(const float4*)(b_in + k0 + 4);
            hr[ks][0] = bv0.x; hr[ks][1] = bv0.y; hr[ks][2] = bv0.z; hr[ks][3] = bv0.w;
            hr[ks][4] = bv1.x; hr[ks][5] = bv1.y; hr[ks][6] = bv1.z; hr[ks][7] = bv1.w;
            #pragma unroll
            for (int c = 0; c < 4; ++c) {
                float4 w0 = *(const float4*)(W_in + c * 64 + k0);
                float4 w1 = *(const float4*)(W_in + c * 64 + k0 + 4);
                hr[ks][0] = fmaf(xc[c], w0.x, hr[ks][0]);
                hr[ks][1] = fmaf(xc[c], w0.y, hr[ks][1]);
                hr[ks][2] = fmaf(xc[c], w0.z, hr[ks][2]);
                hr[ks][3] = fmaf(xc[c], w0.w, hr[ks][3]);
                hr[ks][4] = fmaf(xc[c], w1.x, hr[ks][4]);
                hr[ks][5] = fmaf(xc[c], w1.y, hr[ks][5]);
                hr[ks][6] = fmaf(xc[c], w1.z, hr[ks][6]);
                hr[ks][7] = fmaf(xc[c], w1.w, hr[ks][7]);
            }
        }
    }

    // ---- LayerNorm: 2-step butterfly over the 4 lanes sharing row m ----
    float s = 0.f, q = 0.f;
    #pragma unroll
    for (int ks = 0; ks < 2; ++ks)
        #pragma unroll
        for (int j = 0; j < 8; ++j) { s += hr[ks][j]; q = fmaf(hr[ks][j], hr[ks][j], q); }
    s += __shfl_xor(s, 16, 64); s += __shfl_xor(s, 32, 64);
    q += __shfl_xor(q, 16, 64); q += __shfl_xor(q, 32, 64);
    const float mu = s * (1.f / 64.f);
    const float rstd = rsqrtf(fmaxf(q * (1.f / 64.f) - mu * mu, 0.f) + 1e-5f);
    const float keep = (m < 12) ? 1.f : 0.f;

    bf16x8_t afrag[2];
    #pragma unroll
    for (int ks = 0; ks < 2; ++ks) {
        const int k0 = ks * 32 + lg * 8;
        float4 g0 = *(const float4*)(ln_g + k0);
        float4 g1 = *(const float4*)(ln_g + k0 + 4);
        float4 lb0 = *(const float4*)(ln_b + k0);
        float4 lb1 = *(const float4*)(ln_b + k0 + 4);
        const float gg[8] = {g0.x, g0.y, g0.z, g0.w, g1.x, g1.y, g1.z, g1.w};
        const float bb[8] = {lb0.x, lb0.y, lb0.z, lb0.w, lb1.x, lb1.y, lb1.z, lb1.w};
        #pragma unroll
        for (int j = 0; j < 8; ++j) {
            float v = fmaf((hr[ks][j] - mu) * rstd, gg[j], bb[j]);
            v = fmaxf(v, 0.f) * keep;                 // ReLU; zero junk rows 12-15
            afrag[ks][j] = (__bf16)v;
        }
    }

    // ---- scores tile (it=16) first: sc[col=m][node row] ----
    {
        f32x4_t acc16 = (f32x4_t){0.f, 0.f, 0.f, 0.f};
        #pragma unroll
        for (int ks = 0; ks < 2; ++ks) {
            bf16x8_t bfr = *(const bf16x8_t*)&bfrag[(size_t)((32 + ks) * 64 + lane) * 8];
            acc16 = __builtin_amdgcn_mfma_f32_16x16x32_bf16(afrag[ks], bfr, acc16, 0, 0, 0);
        }
        if (lg < 3) {
            #pragma unroll
            for (int r = 0; r < 4; ++r) sc_sh[wave][m][lg * 4 + r] = acc16[r];
        }
    }
    __asm__ volatile("" ::: "memory");

    // ---- softmax pass 1: coop pairs p=0..3 (3 contiguous neighbors, i0=3a) ----
    {
        const int tp = __float2int_rz((float)lane * 0.083334f);   // lane/12
        const int tn = lane - tp * 12;
        const int ap = (tn * 11) >> 5;                            // tn/3
        if (lane < 48) {
            float ssrc = sc_sh[wave][tp][tn];
            int i0 = 3 * ap;                                      // {0,3,6,9}
            const float* dp = &sc_sh[wave][8 + tp][0];
            float d0 = dp[i0], d1 = dp[i0 + 1], d2 = dp[i0 + 2];
            float t0 = ssrc + d0; t0 = fmaxf(t0, 0.2f * t0);
            float t1 = ssrc + d1; t1 = fmaxf(t1, 0.2f * t1);
            float t2 = ssrc + d2; t2 = fmaxf(t2, 0.2f * t2);
            float e0 = __expf(t0), e1 = __expf(t1), e2 = __expf(t2);
            float inv = 1.f / (e0 + e1 + e2);
            float p0 = e0 * inv, p1 = e1 * inv, p2 = e2 * inv;
            bf16x2_t le, he, lo_, ho_;
            le[0] = (__bf16)p0;  le[1] = (__bf16)p1;
            he[0] = (__bf16)p2;  he[1] = (__bf16)0.f;
            lo_[0] = (__bf16)0.f; lo_[1] = (__bf16)p0;
            ho_[0] = (__bf16)p1;  ho_[1] = (__bf16)p2;
            bool odd = (i0 & 1);
            unsigned int wlo = __builtin_bit_cast(unsigned int, odd ? lo_ : le);
            unsigned int whi = __builtin_bit_cast(unsigned int, odd ? ho_ : he);
            int wd = i0 >> 1;                          // {0,1,3,4}
            unsigned int* rowp = (unsigned int*)&attn_sh[wave][tp][tn][0];
            const uint2 z2 = make_uint2(0u, 0u);
            ((uint2*)rowp)[0] = z2; ((uint2*)rowp)[1] = z2;
            ((uint2*)rowp)[2] = z2; ((uint2*)rowp)[3] = z2;   // dwords 0-7
            rowp[wd] = wlo; rowp[wd + 1] = whi;
        }
    }
    // ---- softmax pass 2: conf pairs p=4..7 (excluded = approach-mates\self) ----
    {
        const int tq = __float2int_rz((float)lane * 0.083334f);
        const int tn = lane - tq * 12;
        const int tp = 4 + tq;
        const int ap = (tn * 11) >> 5;
        const int am_inv = (7 << (3 * ap)) ^ (1 << tn);   // bit set = EXCLUDED
        if (lane < 48) {
            float ssrc = sc_sh[wave][tp][tn];
            float4 d0 = *(const float4*)&sc_sh[wave][8 + tp][0];
            float4 d1 = *(const float4*)&sc_sh[wave][8 + tp][4];
            float4 d2 = *(const float4*)&sc_sh[wave][8 + tp][8];
            float dm[12] = {d0.x, d0.y, d0.z, d0.w, d1.x, d1.y, d1.z, d1.w, d2.x, d2.y, d2.z, d2.w};
            float pr[12]; float ssum = 0.f;
            #pragma unroll
            for (int mm = 0; mm < 12; ++mm) {
                float tv = ssrc + dm[mm];
                tv = fmaxf(tv, 0.2f * tv);                 // leaky_relu(0.2)
                float pp = ((am_inv >> mm) & 1) ? 0.f : __expf(tv);
                ssum += pp; pr[mm] = pp;
            }
            float inv = 1.f / ssum;
            unsigned int w[6];
            #pragma unroll
            for (int qq = 0; qq < 6; ++qq) {
                bf16x2_t pk;
                pk[0] = (__bf16)(pr[2 * qq] * inv);
                pk[1] = (__bf16)(pr[2 * qq + 1] * inv);
                w[qq] = __builtin_bit_cast(unsigned int, pk);
            }
            uint2* arow = (uint2*)&attn_sh[wave][tp][tn][0];
            arow[0] = make_uint2(w[0], w[1]);
            arow[1] = make_uint2(w[2], w[3]);
            arow[2] = make_uint2(w[4], w[5]);
            arow[3] = make_uint2(0u, 0u);                  // cols 12-15 (read by PV lg=3)
        }
    }
    __asm__ volatile("" ::: "memory");

    // ---- fused main-GEMM + PV, streaming one 16-col tile at a time ----
    const int mrow = (m < 12) ? m : 11;                    // clamp: rows 12-15 removed
    const float presc = (lg == 3) ? 0.f : (1.f / 12.f);    // kill garbage C rows 12-15
    unsigned short* scratch = (unsigned short*)&sc_sh[wave][0][0];  // 768 B >= 512 B
    const f32x4_t zero4 = (f32x4_t){0.f, 0.f, 0.f, 0.f};
    #pragma unroll
    for (int p = 0; p < 8; ++p) {
        s16x4_t afr = *(const s16x4_t*)&attn_sh[wave][p][mrow][lg << 2];
        #pragma unroll
        for (int tt = 0; tt < 2; ++tt) {
            const int it = p * 2 + tt;
            f32x4_t acc = (f32x4_t){0.f, 0.f, 0.f, 0.f};
            #pragma unroll
            for (int ks = 0; ks < 2; ++ks) {
                bf16x8_t bfr = *(const bf16x8_t*)&bfrag[(size_t)((it * 2 + ks) * 64 + lane) * 8];
                acc = __builtin_amdgcn_mfma_f32_16x16x32_bf16(afrag[ks], bfr, acc, 0, 0, 0);
            }
            bf16x2_t bv0, bv1;
            bv0[0] = (__bf16)acc[0]; bv0[1] = (__bf16)acc[1];
            bv1[0] = (__bf16)acc[2]; bv1[1] = (__bf16)acc[3];
            s16x4_t bfr2;
            bfr2[0] = (short)__builtin_bit_cast(unsigned int, bv0);
            bfr2[1] = (short)(__builtin_bit_cast(unsigned int, bv0) >> 16);
            bfr2[2] = (short)__builtin_bit_cast(unsigned int, bv1);
            bfr2[3] = (short)(__builtin_bit_cast(unsigned int, bv1) >> 16);
            f32x4_t pv = __builtin_amdgcn_mfma_f32_16x16x16bf16_1k(afr, bfr2, zero4, 0, 0, 0);
            float ss = 0.f;
            #pragma unroll
            for (int r = 0; r < 4; ++r) {
                float xv = pv[r];
                xv = (xv > 0.f) ? xv : (__expf(xv) - 1.f);  // ELU
                ss += xv;
            }
            ss *= presc;                                    // zero lg=3 + 1/12 scale
            ss += __shfl_xor(ss, 16, 64);
            ss += __shfl_xor(ss, 32, 64);
            scratch[p * 32 + tt * 16 + m] = f2bf(ss);       // all lanes; dups same value
        }
    }
    __asm__ volatile("" ::: "memory");
    {
        uint2 v = *(const uint2*)&scratch[lane * 4];
        *(uint2*)&emb[(size_t)g * 256 + lane * 4] = v;      // coalesced 512 B/graph
    }
}

// ---------------------------------------------------------------------------
// Kernel 2: GraphSAGE via MFMA, 2 graphs per wave (B-fragments loaded once,
// applied to both A operands -> halves L2 traffic for sfrag).
// ---------------------------------------------------------------------------
__global__ __launch_bounds__(256) void sage_kernel(
    const unsigned short* __restrict__ emb, const int* __restrict__ mask,
    const unsigned short* __restrict__ sfrag, const float* __restrict__ b_sage,
    float* __restrict__ pooled)
{
    __shared__ float y_sh[4][2][5][128];              // 20480 B
    const int tid = threadIdx.x, wave = tid >> 6, lane = tid & 63;
    const int widx = blockIdx.x * 4 + wave;           // 0..10239
    const int bt0 = widx * 2, bt1 = bt0 + 1;
    const int lg = lane >> 4, row = lane & 15;

    bf16x8_t afrA[8], afrB[8];
    {
        uint4 z = make_uint4(0u, 0u, 0u, 0u);
        if (row < 5) {
            const unsigned short* baseA = emb + (size_t)(bt0 * 5 + row) * 256 + lg * 8;
            const unsigned short* baseB = emb + (size_t)(bt1 * 5 + row) * 256 + lg * 8;
            #pragma unroll
            for (int ks = 0; ks < 8; ++ks) {
                afrA[ks] = *(const bf16x8_t*)(baseA + ks * 32);
                afrB[ks] = *(const bf16x8_t*)(baseB + ks * 32);
            }
        } else {
            #pragma unroll
            for (int ks = 0; ks < 8; ++ks) {
                afrA[ks] = __builtin_bit_cast(bf16x8_t, z);
                afrB[ks] = __builtin_bit_cast(bf16x8_t, z);
            }
        }
    }

    #pragma unroll
    for (int nt = 0; nt < 8; ++nt) {
        f32x4_t accA = (f32x4_t){0.f, 0.f, 0.f, 0.f};
        f32x4_t accB = (f32x4_t){0.f, 0.f, 0.f, 0.f};
        #pragma unroll
        for (int ks = 0; ks < 8; ++ks) {
            bf16x8_t bfr = *(const bf16x8_t*)&sfrag[(size_t)((nt * 8 + ks) * 64 + lane) * 8];
            accA = __builtin_amdgcn_mfma_f32_16x16x32_bf16(afrA[ks], bfr, accA, 0, 0, 0);
            accB = __builtin_amdgcn_mfma_f32_16x16x32_bf16(afrB[ks], bfr, accB, 0, 0, 0);
        }
        #pragma unroll
        for (int r = 0; r < 4; ++r) {
            int rw = lg * 4 + r;
            if (rw < 5) {
                y_sh[wave][0][rw][nt * 16 + row] = accA[r];
                y_sh[wave][1][rw][nt * 16 + row] = accB[r];
            }
        }
    }
    __asm__ volatile("" ::: "memory");

    const float bsg = b_sage[lane];
    #pragma unroll
    for (int gsel = 0; gsel < 2; ++gsel) {
        const int bt = gsel ? bt1 : bt0;
        const int b = bt / 5;
        float md[4];
        #pragma unroll
        for (int d = 0; d < 4; ++d) md[d] = (float)mask[b * 4 + d];
        const float degs = fmaxf(md[0] + md[1] + md[2] + md[3], 1.f);

        float dS[5], dN[5];
        #pragma unroll
        for (int n = 0; n < 5; ++n) {
            dS[n] = y_sh[wave][gsel][n][lane];
            dN[n] = y_sh[wave][gsel][n][64 + lane];
        }
        float agg0 = (md[0] * dN[1] + md[1] * dN[2] + md[2] * dN[3] + md[3] * dN[4]) / degs;
        float p = fmaxf(dS[0] + agg0 + bsg, 0.f);
        #pragma unroll
        for (int d = 0; d < 4; ++d)
            p += fmaxf(dS[d + 1] + md[d] * dN[0] + bsg, 0.f);

        pooled[(size_t)bt * 64 + lane] = p * 0.2f;
    }
}

// ---------------------------------------------------------------------------
// Kernel 3: bidirectional GRU (lanes 0-31 fwd, 32-63 bwd) + output assembly.
// ---------------------------------------------------------------------------
__global__ __launch_bounds__(256) void gru_kernel(
    const float* __restrict__ pooled, const unsigned short* __restrict__ emb,
    const float* __restrict__ Wx_f, const float* __restrict__ Wh_f,
    const float* __restrict__ bx_f, const float* __restrict__ bh_f,
    const float* __restrict__ Wx_b, const float* __restrict__ Wh_b,
    const float* __restrict__ bx_b, const float* __restrict__ bh_b,
    float* __restrict__ out)
{
    __shared__ float x_sh[4][5][64];
    __shared__ float h_sh[4][2][32];
    const int tid = threadIdx.x, wave = tid >> 6, lane = tid & 63;
    const int b = blockIdx.x * 4 + wave;

    #pragma unroll
    for (int t = 0; t < 5; ++t) x_sh[wave][t][lane] = pooled[(size_t)(b * 5 + t) * 64 + lane];

    const int j = lane & 31, dir = lane >> 5;
    const float* Wx = dir ? Wx_b : Wx_f;
    const float* Wh = dir ? Wh_b : Wh_f;
    const float* bx = dir ? bx_b : bx_f;
    const float* bh = dir ? bh_b : bh_f;
    const float bxr = bx[j], bxz = bx[32 + j], bxn = bx[64 + j];
    const float bhr = bh[j], bhz = bh[32 + j], bhn = bh[64 + j];
    float h = 0.f;
    __syncthreads();

    for (int s = 0; s < 5; ++s) {
        const int t = dir ? (4 - s) : s;
        h_sh[wave][dir][j] = h;
        __syncthreads();
        float xr = bxr, xz = bxz, xn = bxn;
        for (int f = 0; f < 64; ++f) {
            float xv = x_sh[wave][t][f];
            xr = fmaf(xv, Wx[f * 96 + j], xr);
            xz = fmaf(xv, Wx[f * 96 + 32 + j], xz);
            xn = fmaf(xv, Wx[f * 96 + 64 + j], xn);
        }
        float hr = bhr, hz = bhz, hn = bhn;
        for (int f = 0; f < 32; ++f) {
            float hv = h_sh[wave][dir][f];
            hr = fmaf(hv, Wh[f * 96 + j], hr);
            hz = fmaf(hv, Wh[f * 96 + 32 + j], hz);
            hn = fmaf(hv, Wh[f * 96 + 64 + j], hn);
        }
        float rr = 1.f / (1.f + __expf(-(xr + hr)));
        float zz = 1.f / (1.f + __expf(-(xz + hz)));
        float ni = xn + rr * hn;
        ni = fminf(fmaxf(ni, -15.f), 15.f);
        float e2 = __expf(2.f * ni);
        float nn = (e2 - 1.f) / (e2 + 1.f);
        h = (1.f - zz) * nn + zz * h;
        __syncthreads();
    }

    out[(size_t)b * 320 + 256 + dir * 32 + j] = h;
    const unsigned short* se = emb + (size_t)((b * 5 + 4) * 5) * 256;
    #pragma unroll
    for (int c = 0; c < 4; ++c)
        out[(size_t)b * 320 + c * 64 + lane] = __builtin_bit_cast(float, ((unsigned int)se[c * 64 + lane]) << 16);
}

// ---------------------------------------------------------------------------
extern "C" void kernel_launch(void* const* d_in, const int* in_sizes, int n_in,
                              void* d_out, int out_size, void* d_ws, size_t ws_size,
                              hipStream_t stream) {
    (void)in_sizes; (void)n_in; (void)out_size; (void)ws_size;
    const float* self_feat = (const float*)d_in[0];
    const float* nbr_feat  = (const float*)d_in[1];
    const float* W_in   = (const float*)d_in[2];
    const float* b_in_  = (const float*)d_in[3];
    const float* ln_g   = (const float*)d_in[4];
    const float* ln_b   = (const float*)d_in[5];
    const float* W_coop = (const float*)d_in[6];
    const float* as_c   = (const float*)d_in[7];
    const float* ad_c   = (const float*)d_in[8];
    const float* W_conf = (const float*)d_in[9];
    const float* as_f   = (const float*)d_in[10];
    const float* ad_f   = (const float*)d_in[11];
    const float* W_self = (const float*)d_in[12];
    const float* W_neigh= (const float*)d_in[13];
    const float* b_sage = (const float*)d_in[14];
    const float* Wx_f   = (const float*)d_in[15];
    const float* Wh_f   = (const float*)d_in[16];
    const float* bx_f   = (const float*)d_in[17];
    const float* bh_f   = (const float*)d_in[18];
    const float* Wx_b   = (const float*)d_in[19];
    const float* Wh_b   = (const float*)d_in[20];
    const float* bx_b   = (const float*)d_in[21];
    const float* bh_b   = (const float*)d_in[22];
    const int*   mask   = (const int*)d_in[25];
    float* out = (float*)d_out;

    unsigned short* bfrag = (unsigned short*)((char*)d_ws + OFF_BFRAG);
    unsigned short* sfrag = (unsigned short*)((char*)d_ws + OFF_SFRAG);
    unsigned short* emb   = (unsigned short*)((char*)d_ws + OFF_EMB);
    float*          pooled= (float*)((char*)d_ws + OFF_POOLED);

    prep_kernel<<<32, 256, 0, stream>>>(W_coop, as_c, ad_c, W_conf, as_f, ad_f,
                                        W_self, W_neigh, bfrag, sfrag);
    gat_kernel<<<GTOT / 4, 256, 0, stream>>>(self_feat, nbr_feat, W_in, b_in_, ln_g, ln_b,
                                             bfrag, emb);
    sage_kernel<<<(BB * TT) / 8, 256, 0, stream>>>(emb, mask, sfrag, b_sage, pooled);
    gru_kernel<<<BB / 4, 256, 0, stream>>>(pooled, emb,
        Wx_f, Wh_f, bx_f, bh_f, Wx_b, Wh_b, bx_b, bh_b, out);
}